// Round 1
// baseline (555.243 us; speedup 1.0000x reference)
//
#include <hip/hip_runtime.h>
#include <math.h>

#define EPSV 1e-6f
#define NSL  0.2f
#define BB   2
#define NN   2048
#define CINV 64
#define QKD  128
#define HH   8
#define HD   16

// ---------------------------------------------------------------------------
// pre_q: qf = ev_nonlin(qfts @ w_in), q = ev_layernorm(heads(qf @ w_h))
// one block (128 threads) per token. Writes Qb as [h][b][n][f*16+d], f32.
// ---------------------------------------------------------------------------
__global__ __launch_bounds__(128) void pre_q_kernel(
    const float* __restrict__ x_in, const float* __restrict__ w_in,
    const float* __restrict__ w1, const float* __restrict__ b1,
    const float* __restrict__ w2, const float* __restrict__ b2,
    const float* __restrict__ w_h, float* __restrict__ Qb)
{
  const int t = blockIdx.x;        // b*N + n
  const int j = threadIdx.x;       // 0..127 = output channel
  __shared__ float xs[192];
  __shared__ float norm_s[128];
  __shared__ float h_s[64];
  __shared__ float qf_s[3][128];

  if (j < 96) ((float2*)xs)[j] = ((const float2*)(x_in + (size_t)t * 192))[j];
  __syncthreads();

  float p0 = 0.f, p1 = 0.f, p2 = 0.f;
  #pragma unroll
  for (int c = 0; c < 64; ++c) {
    float wv = w_in[c * 128 + j];
    p0 += xs[c] * wv; p1 += xs[64 + c] * wv; p2 += xs[128 + c] * wv;
  }
  float nn = sqrtf(p0 * p0 + p1 * p1 + p2 * p2);
  bool zero = nn <= EPSV;
  float np = nn + EPSV;
  norm_s[j] = np;
  __syncthreads();

  if (j < 64) {
    float a = b1[j];
    #pragma unroll
    for (int c = 0; c < 128; ++c) a += norm_s[c] * w1[c * 64 + j];
    h_s[j] = a > 0.f ? a : NSL * a;
  }
  __syncthreads();

  float bn = b2[j] + np;
  #pragma unroll
  for (int i = 0; i < 64; ++i) bn += h_s[i] * w2[i * 128 + j];
  float ratio = zero ? 1.f : bn / np;
  qf_s[0][j] = p0 * ratio; qf_s[1][j] = p1 * ratio; qf_s[2][j] = p2 * ratio;
  __syncthreads();

  float q0 = 0.f, q1 = 0.f, q2 = 0.f;
  #pragma unroll
  for (int c = 0; c < 128; ++c) {
    float wv = w_h[c * 128 + j];
    q0 += qf_s[0][c] * wv; q1 += qf_s[1][c] * wv; q2 += qf_s[2][c] * wv;
  }
  // EV layernorm per head (16 consecutive channels = one head)
  float ss = q0 * q0 + q1 * q1 + q2 * q2;
  ss += __shfl_xor(ss, 1, 16);
  ss += __shfl_xor(ss, 2, 16);
  ss += __shfl_xor(ss, 4, 16);
  ss += __shfl_xor(ss, 8, 16);
  float inv = 1.f / (sqrtf(ss * (1.f / 16.f)) + EPSV);
  const int hh = j >> 4, dd = j & 15;
  float* qd = Qb + ((size_t)hh * BB * NN + t) * 48 + dd;
  qd[0]  = q0 * inv;
  qd[16] = q1 * inv;
  qd[32] = q2 * inv;
}

// ---------------------------------------------------------------------------
// pre_kv: kf = ev_nonlin(kvfts @ w_in); K = layernorm(kf @ w_k) ; V = kf @ w_v
// ---------------------------------------------------------------------------
__global__ __launch_bounds__(128) void pre_kv_kernel(
    const float* __restrict__ x_in, const float* __restrict__ w_in,
    const float* __restrict__ w1, const float* __restrict__ b1,
    const float* __restrict__ w2, const float* __restrict__ b2,
    const float* __restrict__ w_k, const float* __restrict__ w_v,
    float* __restrict__ Kb, float* __restrict__ Vb)
{
  const int t = blockIdx.x;
  const int j = threadIdx.x;
  __shared__ float xs[192];
  __shared__ float norm_s[128];
  __shared__ float h_s[64];
  __shared__ float kf_s[3][128];

  if (j < 96) ((float2*)xs)[j] = ((const float2*)(x_in + (size_t)t * 192))[j];
  __syncthreads();

  float p0 = 0.f, p1 = 0.f, p2 = 0.f;
  #pragma unroll
  for (int c = 0; c < 64; ++c) {
    float wv = w_in[c * 128 + j];
    p0 += xs[c] * wv; p1 += xs[64 + c] * wv; p2 += xs[128 + c] * wv;
  }
  float nn = sqrtf(p0 * p0 + p1 * p1 + p2 * p2);
  bool zero = nn <= EPSV;
  float np = nn + EPSV;
  norm_s[j] = np;
  __syncthreads();

  if (j < 64) {
    float a = b1[j];
    #pragma unroll
    for (int c = 0; c < 128; ++c) a += norm_s[c] * w1[c * 64 + j];
    h_s[j] = a > 0.f ? a : NSL * a;
  }
  __syncthreads();

  float bn = b2[j] + np;
  #pragma unroll
  for (int i = 0; i < 64; ++i) bn += h_s[i] * w2[i * 128 + j];
  float ratio = zero ? 1.f : bn / np;
  kf_s[0][j] = p0 * ratio; kf_s[1][j] = p1 * ratio; kf_s[2][j] = p2 * ratio;
  __syncthreads();

  const int hh = j >> 4, dd = j & 15;

  // K head projection + layernorm
  {
    float q0 = 0.f, q1 = 0.f, q2 = 0.f;
    #pragma unroll
    for (int c = 0; c < 128; ++c) {
      float wv = w_k[c * 128 + j];
      q0 += kf_s[0][c] * wv; q1 += kf_s[1][c] * wv; q2 += kf_s[2][c] * wv;
    }
    float ss = q0 * q0 + q1 * q1 + q2 * q2;
    ss += __shfl_xor(ss, 1, 16);
    ss += __shfl_xor(ss, 2, 16);
    ss += __shfl_xor(ss, 4, 16);
    ss += __shfl_xor(ss, 8, 16);
    float inv = 1.f / (sqrtf(ss * (1.f / 16.f)) + EPSV);
    float* kd = Kb + ((size_t)hh * BB * NN + t) * 48 + dd;
    kd[0]  = q0 * inv;
    kd[16] = q1 * inv;
    kd[32] = q2 * inv;
  }
  // V head projection (no layernorm)
  {
    float v0 = 0.f, v1 = 0.f, v2 = 0.f;
    #pragma unroll
    for (int c = 0; c < 128; ++c) {
      float wv = w_v[c * 128 + j];
      v0 += kf_s[0][c] * wv; v1 += kf_s[1][c] * wv; v2 += kf_s[2][c] * wv;
    }
    float* vd = Vb + ((size_t)hh * BB * NN + t) * 48 + dd;
    vd[0]  = v0;
    vd[16] = v1;
    vd[32] = v2;
  }
}

// ---------------------------------------------------------------------------
// attention: flash-style, f32 VALU.
// grid (N/32, H*B), 256 threads. Thread t: q-row r=t>>3, K-subset sub=t&7.
// K/V tile of 64 rows staged in LDS (row stride 52 floats: conflict-free).
// Writes Ob as [b][q][f][h*16+d] f32.
// ---------------------------------------------------------------------------
#define QT 32
#define KT 64
#define KP 52

__global__ __launch_bounds__(256) void attn_kernel(
    const float* __restrict__ Qb, const float* __restrict__ Kb,
    const float* __restrict__ Vb, float* __restrict__ Ob)
{
  const int hb = blockIdx.y;          // h*B + b
  const int q0 = blockIdx.x * QT;
  const int tid = threadIdx.x;
  const int r = tid >> 3;             // 0..31
  const int sub = tid & 7;            // 0..7

  __shared__ __align__(16) float ks[KT][KP];
  __shared__ __align__(16) float vs[KT][KP];

  float q[48];
  {
    const float4* qp = (const float4*)(Qb + ((size_t)hb * NN + q0 + r) * 48);
    #pragma unroll
    for (int i = 0; i < 12; ++i) {
      float4 v4 = qp[i];
      q[i * 4 + 0] = v4.x * 0.25f; q[i * 4 + 1] = v4.y * 0.25f;
      q[i * 4 + 2] = v4.z * 0.25f; q[i * 4 + 3] = v4.w * 0.25f;
    }
  }
  float acc[48];
  #pragma unroll
  for (int c = 0; c < 48; ++c) acc[c] = 0.f;
  float m = -1e30f, l = 0.f;

  const float* Kbase = Kb + (size_t)hb * NN * 48;
  const float* Vbase = Vb + (size_t)hb * NN * 48;

  for (int k0 = 0; k0 < NN; k0 += KT) {
    __syncthreads();
    const float4* Kt = (const float4*)(Kbase + (size_t)k0 * 48);
    const float4* Vt = (const float4*)(Vbase + (size_t)k0 * 48);
    #pragma unroll
    for (int it = 0; it < 3; ++it) {
      int i = tid + it * 256;          // 768 float4s total
      int row = i / 12, col = (i % 12) * 4;
      *(float4*)&ks[row][col] = Kt[i];
      *(float4*)&vs[row][col] = Vt[i];
    }
    __syncthreads();

    float s[8];
    #pragma unroll
    for (int jj = 0; jj < 8; ++jj) {
      const float4* kr4 = (const float4*)&ks[jj * 8 + sub][0];
      float d0 = 0.f;
      #pragma unroll
      for (int i4 = 0; i4 < 12; ++i4) {
        float4 kv = kr4[i4];
        d0 += q[i4 * 4 + 0] * kv.x + q[i4 * 4 + 1] * kv.y
            + q[i4 * 4 + 2] * kv.z + q[i4 * 4 + 3] * kv.w;
      }
      s[jj] = d0;
    }
    float tm = s[0];
    #pragma unroll
    for (int jj = 1; jj < 8; ++jj) tm = fmaxf(tm, s[jj]);
    float mnew = fmaxf(m, tm);
    float fsc = expf(m - mnew);
    if (fsc < 1.f) {
      l *= fsc;
      #pragma unroll
      for (int c = 0; c < 48; ++c) acc[c] *= fsc;
    }
    #pragma unroll
    for (int jj = 0; jj < 8; ++jj) {
      float p = expf(s[jj] - mnew);
      l += p;
      const float4* vr4 = (const float4*)&vs[jj * 8 + sub][0];
      #pragma unroll
      for (int i4 = 0; i4 < 12; ++i4) {
        float4 vv = vr4[i4];
        acc[i4 * 4 + 0] += p * vv.x; acc[i4 * 4 + 1] += p * vv.y;
        acc[i4 * 4 + 2] += p * vv.z; acc[i4 * 4 + 3] += p * vv.w;
      }
    }
    m = mnew;
  }

  // combine the 8 K-subsets of each q-row (8 consecutive lanes)
  #pragma unroll
  for (int mask = 1; mask < 8; mask <<= 1) {
    float mo = __shfl_xor(m, mask, 8);
    float lo = __shfl_xor(l, mask, 8);
    float mn = fmaxf(m, mo);
    float fs = expf(m - mn), fo = expf(mo - mn);
    l = l * fs + lo * fo;
    #pragma unroll
    for (int c = 0; c < 48; ++c)
      acc[c] = acc[c] * fs + __shfl_xor(acc[c], mask, 8) * fo;
    m = mn;
  }
  float invl = 1.f / l;

  const int h_ = hb >> 1, b_ = hb & 1;   // hb = h*B + b, B = 2
  #pragma unroll
  for (int e = 0; e < 6; ++e) {
    int c = sub * 6 + e;
    int f = c >> 4, d = c & 15;
    Ob[(((size_t)(b_ * NN + q0 + r)) * 3 + f) * 128 + h_ * 16 + d] = acc[c] * invl;
  }
}

// ---------------------------------------------------------------------------
// out: out = ev_nonlin(resi @ w_out). One block (128 threads) per token.
// ---------------------------------------------------------------------------
__global__ __launch_bounds__(128) void out_kernel(
    const float* __restrict__ Ob, const float* __restrict__ w_out,
    const float* __restrict__ w1, const float* __restrict__ b1,
    const float* __restrict__ w2, const float* __restrict__ b2,
    float* __restrict__ out)
{
  const int t = blockIdx.x;
  const int j = threadIdx.x;
  __shared__ float rs[384];
  __shared__ float norm_s[128];
  __shared__ float h_s[64];

  rs[j]       = Ob[(size_t)t * 384 + j];
  rs[j + 128] = Ob[(size_t)t * 384 + 128 + j];
  rs[j + 256] = Ob[(size_t)t * 384 + 256 + j];
  __syncthreads();

  float p0 = 0.f, p1 = 0.f, p2 = 0.f;
  #pragma unroll
  for (int c = 0; c < 128; ++c) {
    float wv = w_out[c * 128 + j];
    p0 += rs[c] * wv; p1 += rs[128 + c] * wv; p2 += rs[256 + c] * wv;
  }
  float nn = sqrtf(p0 * p0 + p1 * p1 + p2 * p2);
  bool zero = nn <= EPSV;
  float np = nn + EPSV;
  norm_s[j] = np;
  __syncthreads();

  if (j < 64) {
    float a = b1[j];
    #pragma unroll
    for (int c = 0; c < 128; ++c) a += norm_s[c] * w1[c * 64 + j];
    h_s[j] = a > 0.f ? a : NSL * a;
  }
  __syncthreads();

  float bn = b2[j] + np;
  #pragma unroll
  for (int i = 0; i < 64; ++i) bn += h_s[i] * w2[i * 128 + j];
  float ratio = zero ? 1.f : bn / np;

  out[(size_t)t * 384 + j]       = p0 * ratio;
  out[(size_t)t * 384 + 128 + j] = p1 * ratio;
  out[(size_t)t * 384 + 256 + j] = p2 * ratio;
}

// ---------------------------------------------------------------------------
extern "C" void kernel_launch(void* const* d_in, const int* in_sizes, int n_in,
                              void* d_out, int out_size, void* d_ws, size_t ws_size,
                              hipStream_t stream) {
  const float* qfts   = (const float*)d_in[0];
  const float* kvfts  = (const float*)d_in[1];
  const float* w_q_in = (const float*)d_in[2];
  const float* q_w1   = (const float*)d_in[3];
  const float* q_b1   = (const float*)d_in[4];
  const float* q_w2   = (const float*)d_in[5];
  const float* q_b2   = (const float*)d_in[6];
  const float* w_kv_in= (const float*)d_in[7];
  const float* kv_w1  = (const float*)d_in[8];
  const float* kv_b1  = (const float*)d_in[9];
  const float* kv_w2  = (const float*)d_in[10];
  const float* kv_b2  = (const float*)d_in[11];
  const float* w_q    = (const float*)d_in[12];
  const float* w_k    = (const float*)d_in[13];
  const float* w_v    = (const float*)d_in[14];
  const float* w_out  = (const float*)d_in[15];
  const float* o_w1   = (const float*)d_in[16];
  const float* o_b1   = (const float*)d_in[17];
  const float* o_w2   = (const float*)d_in[18];
  const float* o_b2   = (const float*)d_in[19];

  const size_t per = (size_t)HH * BB * NN * 48;   // 1.57M floats
  float* Qbuf = (float*)d_ws;
  float* Kbuf = Qbuf + per;
  float* Vbuf = Kbuf + per;
  float* Obuf = Vbuf + per;

  pre_q_kernel<<<BB * NN, 128, 0, stream>>>(qfts, w_q_in, q_w1, q_b1, q_w2, q_b2, w_q, Qbuf);
  pre_kv_kernel<<<BB * NN, 128, 0, stream>>>(kvfts, w_kv_in, kv_w1, kv_b1, kv_w2, kv_b2,
                                             w_k, w_v, Kbuf, Vbuf);
  dim3 ag(NN / QT, HH * BB);
  attn_kernel<<<ag, 256, 0, stream>>>(Qbuf, Kbuf, Vbuf, Obuf);
  out_kernel<<<BB * NN, 128, 0, stream>>>(Obuf, w_out, o_w1, o_b1, o_w2, o_b2, (float*)d_out);
}

// Round 2
// 552.007 us; speedup vs baseline: 1.0059x; 1.0059x over previous
//
#include <hip/hip_runtime.h>
#include <math.h>

#define EPSV 1e-6f
#define NSL  0.2f
#define BB   2
#define NN   2048
#define HH   8
#define TB   8     // tokens per block in pre/out kernels

// ---------------------------------------------------------------------------
// pre_q: qf = ev_nonlin(qfts @ w_in), q = ev_layernorm(heads(qf @ w_h))
// 8 tokens per block (128 threads). Writes Qb as [h][b][n][f*16+d], f32.
// ---------------------------------------------------------------------------
__global__ __launch_bounds__(128) void pre_q_kernel(
    const float* __restrict__ x_in, const float* __restrict__ w_in,
    const float* __restrict__ w1, const float* __restrict__ b1,
    const float* __restrict__ w2, const float* __restrict__ b2,
    const float* __restrict__ w_h, float* __restrict__ Qb)
{
  const int t0 = blockIdx.x * TB;
  const int j = threadIdx.x;
  __shared__ float xs[TB][192];
  __shared__ float norm_s[TB][128];
  __shared__ float h_s[TB][64];
  __shared__ float qf_s[TB][3][128];

  {
    const float4* src = (const float4*)(x_in + (size_t)t0 * 192);
    float4* dst = (float4*)&xs[0][0];
    #pragma unroll
    for (int i = 0; i < 3; ++i) dst[j + i * 128] = src[j + i * 128];
  }
  __syncthreads();

  float p0[TB], p1[TB], p2[TB];
  #pragma unroll
  for (int t = 0; t < TB; ++t) { p0[t] = 0.f; p1[t] = 0.f; p2[t] = 0.f; }
  for (int c = 0; c < 64; ++c) {
    float wv = w_in[c * 128 + j];
    #pragma unroll
    for (int t = 0; t < TB; ++t) {
      p0[t] += xs[t][c] * wv; p1[t] += xs[t][64 + c] * wv; p2[t] += xs[t][128 + c] * wv;
    }
  }
  float np[TB]; int zmask = 0;
  #pragma unroll
  for (int t = 0; t < TB; ++t) {
    float nn = sqrtf(p0[t] * p0[t] + p1[t] * p1[t] + p2[t] * p2[t]);
    if (nn <= EPSV) zmask |= (1 << t);
    np[t] = nn + EPSV;
    norm_s[t][j] = np[t];
  }
  __syncthreads();

  {
    const int jc = j & 63;
    const int tb = (j >> 6) * 4;
    float a0 = b1[jc], a1 = a0, a2 = a0, a3 = a0;
    for (int c = 0; c < 128; ++c) {
      float wv = w1[c * 64 + jc];
      a0 += norm_s[tb + 0][c] * wv; a1 += norm_s[tb + 1][c] * wv;
      a2 += norm_s[tb + 2][c] * wv; a3 += norm_s[tb + 3][c] * wv;
    }
    h_s[tb + 0][jc] = a0 > 0.f ? a0 : NSL * a0;
    h_s[tb + 1][jc] = a1 > 0.f ? a1 : NSL * a1;
    h_s[tb + 2][jc] = a2 > 0.f ? a2 : NSL * a2;
    h_s[tb + 3][jc] = a3 > 0.f ? a3 : NSL * a3;
  }
  __syncthreads();

  float bn[TB];
  {
    float b2j = b2[j];
    #pragma unroll
    for (int t = 0; t < TB; ++t) bn[t] = b2j + np[t];
    for (int i = 0; i < 64; ++i) {
      float wv = w2[i * 128 + j];
      #pragma unroll
      for (int t = 0; t < TB; ++t) bn[t] += h_s[t][i] * wv;
    }
  }
  #pragma unroll
  for (int t = 0; t < TB; ++t) {
    float ratio = (zmask >> t) & 1 ? 1.f : bn[t] / np[t];
    qf_s[t][0][j] = p0[t] * ratio; qf_s[t][1][j] = p1[t] * ratio; qf_s[t][2][j] = p2[t] * ratio;
  }
  __syncthreads();

  float q0[TB], q1[TB], q2[TB];
  #pragma unroll
  for (int t = 0; t < TB; ++t) { q0[t] = 0.f; q1[t] = 0.f; q2[t] = 0.f; }
  for (int c = 0; c < 128; ++c) {
    float wv = w_h[c * 128 + j];
    #pragma unroll
    for (int t = 0; t < TB; ++t) {
      q0[t] += qf_s[t][0][c] * wv; q1[t] += qf_s[t][1][c] * wv; q2[t] += qf_s[t][2][c] * wv;
    }
  }
  const int hh = j >> 4, dd = j & 15;
  #pragma unroll
  for (int t = 0; t < TB; ++t) {
    float ss = q0[t] * q0[t] + q1[t] * q1[t] + q2[t] * q2[t];
    ss += __shfl_xor(ss, 1, 16);
    ss += __shfl_xor(ss, 2, 16);
    ss += __shfl_xor(ss, 4, 16);
    ss += __shfl_xor(ss, 8, 16);
    float inv = 1.f / (sqrtf(ss * (1.f / 16.f)) + EPSV);
    float* qd = Qb + ((size_t)hh * BB * NN + t0 + t) * 48 + dd;
    qd[0] = q0[t] * inv; qd[16] = q1[t] * inv; qd[32] = q2[t] * inv;
  }
}

// ---------------------------------------------------------------------------
// pre_kv: kf = ev_nonlin(kvfts @ w_in); K = layernorm(kf @ w_k); V = kf @ w_v
// ---------------------------------------------------------------------------
__global__ __launch_bounds__(128) void pre_kv_kernel(
    const float* __restrict__ x_in, const float* __restrict__ w_in,
    const float* __restrict__ w1, const float* __restrict__ b1,
    const float* __restrict__ w2, const float* __restrict__ b2,
    const float* __restrict__ w_k, const float* __restrict__ w_v,
    float* __restrict__ Kb, float* __restrict__ Vb)
{
  const int t0 = blockIdx.x * TB;
  const int j = threadIdx.x;
  __shared__ float xs[TB][192];
  __shared__ float norm_s[TB][128];
  __shared__ float h_s[TB][64];
  __shared__ float kf_s[TB][3][128];

  {
    const float4* src = (const float4*)(x_in + (size_t)t0 * 192);
    float4* dst = (float4*)&xs[0][0];
    #pragma unroll
    for (int i = 0; i < 3; ++i) dst[j + i * 128] = src[j + i * 128];
  }
  __syncthreads();

  float p0[TB], p1[TB], p2[TB];
  #pragma unroll
  for (int t = 0; t < TB; ++t) { p0[t] = 0.f; p1[t] = 0.f; p2[t] = 0.f; }
  for (int c = 0; c < 64; ++c) {
    float wv = w_in[c * 128 + j];
    #pragma unroll
    for (int t = 0; t < TB; ++t) {
      p0[t] += xs[t][c] * wv; p1[t] += xs[t][64 + c] * wv; p2[t] += xs[t][128 + c] * wv;
    }
  }
  float np[TB]; int zmask = 0;
  #pragma unroll
  for (int t = 0; t < TB; ++t) {
    float nn = sqrtf(p0[t] * p0[t] + p1[t] * p1[t] + p2[t] * p2[t]);
    if (nn <= EPSV) zmask |= (1 << t);
    np[t] = nn + EPSV;
    norm_s[t][j] = np[t];
  }
  __syncthreads();

  {
    const int jc = j & 63;
    const int tb = (j >> 6) * 4;
    float a0 = b1[jc], a1 = a0, a2 = a0, a3 = a0;
    for (int c = 0; c < 128; ++c) {
      float wv = w1[c * 64 + jc];
      a0 += norm_s[tb + 0][c] * wv; a1 += norm_s[tb + 1][c] * wv;
      a2 += norm_s[tb + 2][c] * wv; a3 += norm_s[tb + 3][c] * wv;
    }
    h_s[tb + 0][jc] = a0 > 0.f ? a0 : NSL * a0;
    h_s[tb + 1][jc] = a1 > 0.f ? a1 : NSL * a1;
    h_s[tb + 2][jc] = a2 > 0.f ? a2 : NSL * a2;
    h_s[tb + 3][jc] = a3 > 0.f ? a3 : NSL * a3;
  }
  __syncthreads();

  float bn[TB];
  {
    float b2j = b2[j];
    #pragma unroll
    for (int t = 0; t < TB; ++t) bn[t] = b2j + np[t];
    for (int i = 0; i < 64; ++i) {
      float wv = w2[i * 128 + j];
      #pragma unroll
      for (int t = 0; t < TB; ++t) bn[t] += h_s[t][i] * wv;
    }
  }
  #pragma unroll
  for (int t = 0; t < TB; ++t) {
    float ratio = (zmask >> t) & 1 ? 1.f : bn[t] / np[t];
    kf_s[t][0][j] = p0[t] * ratio; kf_s[t][1][j] = p1[t] * ratio; kf_s[t][2][j] = p2[t] * ratio;
  }
  __syncthreads();

  const int hh = j >> 4, dd = j & 15;

  {
    float q0[TB], q1[TB], q2[TB];
    #pragma unroll
    for (int t = 0; t < TB; ++t) { q0[t] = 0.f; q1[t] = 0.f; q2[t] = 0.f; }
    for (int c = 0; c < 128; ++c) {
      float wv = w_k[c * 128 + j];
      #pragma unroll
      for (int t = 0; t < TB; ++t) {
        q0[t] += kf_s[t][0][c] * wv; q1[t] += kf_s[t][1][c] * wv; q2[t] += kf_s[t][2][c] * wv;
      }
    }
    #pragma unroll
    for (int t = 0; t < TB; ++t) {
      float ss = q0[t] * q0[t] + q1[t] * q1[t] + q2[t] * q2[t];
      ss += __shfl_xor(ss, 1, 16);
      ss += __shfl_xor(ss, 2, 16);
      ss += __shfl_xor(ss, 4, 16);
      ss += __shfl_xor(ss, 8, 16);
      float inv = 1.f / (sqrtf(ss * (1.f / 16.f)) + EPSV);
      float* kd = Kb + ((size_t)hh * BB * NN + t0 + t) * 48 + dd;
      kd[0] = q0[t] * inv; kd[16] = q1[t] * inv; kd[32] = q2[t] * inv;
    }
  }
  {
    float v0[TB], v1[TB], v2[TB];
    #pragma unroll
    for (int t = 0; t < TB; ++t) { v0[t] = 0.f; v1[t] = 0.f; v2[t] = 0.f; }
    for (int c = 0; c < 128; ++c) {
      float wv = w_v[c * 128 + j];
      #pragma unroll
      for (int t = 0; t < TB; ++t) {
        v0[t] += kf_s[t][0][c] * wv; v1[t] += kf_s[t][1][c] * wv; v2[t] += kf_s[t][2][c] * wv;
      }
    }
    #pragma unroll
    for (int t = 0; t < TB; ++t) {
      float* vd = Vb + ((size_t)hh * BB * NN + t0 + t) * 48 + dd;
      vd[0] = v0[t]; vd[16] = v1[t]; vd[32] = v2[t];
    }
  }
}

// ---------------------------------------------------------------------------
// attention: flash-style, f32 VALU, no register spills.
// grid (N/32, H*B), 256 threads. Thread (r=tid>>3, sub=tid&7).
// Score phase: thread computes 8 scores for k-rows {jj*8+sub}.
// PV phase: thread owns output dims [sub*6, sub*6+6), accumulates over all 64 k.
// p passes through LDS (stride 68 floats: float4 reads conflict-free).
// ---------------------------------------------------------------------------
#define QT 32
#define KT 64
#define KP 52
#define PP 68

__global__ __launch_bounds__(256) void attn_kernel(
    const float* __restrict__ Qb, const float* __restrict__ Kb,
    const float* __restrict__ Vb, float* __restrict__ Ob)
{
  const int hb = blockIdx.y;
  const int q0 = blockIdx.x * QT;
  const int tid = threadIdx.x;
  const int r = tid >> 3;
  const int sub = tid & 7;

  __shared__ __align__(16) float ks[KT][KP];
  __shared__ __align__(16) float vs[KT][KP];
  __shared__ __align__(16) float ps[QT][PP];

  float q[48];
  {
    const float4* qp = (const float4*)(Qb + ((size_t)hb * NN + q0 + r) * 48);
    #pragma unroll
    for (int i = 0; i < 12; ++i) {
      float4 v4 = qp[i];
      q[i * 4 + 0] = v4.x * 0.25f; q[i * 4 + 1] = v4.y * 0.25f;
      q[i * 4 + 2] = v4.z * 0.25f; q[i * 4 + 3] = v4.w * 0.25f;
    }
  }
  float acc[6] = {0.f, 0.f, 0.f, 0.f, 0.f, 0.f};
  float m = -1e30f, l = 0.f;

  const float* Kbase = Kb + (size_t)hb * NN * 48;
  const float* Vbase = Vb + (size_t)hb * NN * 48;

  for (int k0 = 0; k0 < NN; k0 += KT) {
    __syncthreads();
    const float4* Kt = (const float4*)(Kbase + (size_t)k0 * 48);
    const float4* Vt = (const float4*)(Vbase + (size_t)k0 * 48);
    #pragma unroll
    for (int it = 0; it < 3; ++it) {
      int i = tid + it * 256;
      int row = i / 12, col = (i % 12) * 4;
      *(float4*)&ks[row][col] = Kt[i];
      *(float4*)&vs[row][col] = Vt[i];
    }
    __syncthreads();

    // ---- scores for k-rows jj*8+sub ----
    float s[8];
    #pragma unroll
    for (int jj = 0; jj < 8; ++jj) {
      const float4* kr4 = (const float4*)&ks[jj * 8 + sub][0];
      float d0 = 0.f;
      #pragma unroll
      for (int i4 = 0; i4 < 12; ++i4) {
        float4 kv = kr4[i4];
        d0 += q[i4 * 4 + 0] * kv.x + q[i4 * 4 + 1] * kv.y
            + q[i4 * 4 + 2] * kv.z + q[i4 * 4 + 3] * kv.w;
      }
      s[jj] = d0;
    }
    float tm = fmaxf(fmaxf(fmaxf(s[0], s[1]), fmaxf(s[2], s[3])),
                     fmaxf(fmaxf(s[4], s[5]), fmaxf(s[6], s[7])));
    tm = fmaxf(tm, __shfl_xor(tm, 1, 8));
    tm = fmaxf(tm, __shfl_xor(tm, 2, 8));
    tm = fmaxf(tm, __shfl_xor(tm, 4, 8));
    float mnew = fmaxf(m, tm);
    float fsc = __expf(m - mnew);
    l *= fsc;
    #pragma unroll
    for (int c = 0; c < 6; ++c) acc[c] *= fsc;
    float lp = 0.f;
    #pragma unroll
    for (int jj = 0; jj < 8; ++jj) {
      float p = __expf(s[jj] - mnew);
      lp += p;
      ps[r][jj * 8 + sub] = p;
    }
    lp += __shfl_xor(lp, 1, 8);
    lp += __shfl_xor(lp, 2, 8);
    lp += __shfl_xor(lp, 4, 8);
    l += lp;
    m = mnew;
    __syncthreads();

    // ---- PV: dims sub*6 .. sub*6+5 over all 64 k ----
    const float4* pr = (const float4*)&ps[r][0];
    #pragma unroll
    for (int k4 = 0; k4 < 16; ++k4) {
      float4 p4 = pr[k4];
      float pa[4] = {p4.x, p4.y, p4.z, p4.w};
      #pragma unroll
      for (int kk = 0; kk < 4; ++kk) {
        float pk = pa[kk];
        const float* vr = &vs[k4 * 4 + kk][sub * 6];
        float2 va = *(const float2*)(vr);
        float2 vb = *(const float2*)(vr + 2);
        float2 vc = *(const float2*)(vr + 4);
        acc[0] += pk * va.x; acc[1] += pk * va.y;
        acc[2] += pk * vb.x; acc[3] += pk * vb.y;
        acc[4] += pk * vc.x; acc[5] += pk * vc.y;
      }
    }
  }

  float invl = 1.f / l;
  const int h_ = hb >> 1, b_ = hb & 1;   // hb = h*B + b, B = 2
  #pragma unroll
  for (int e = 0; e < 6; ++e) {
    int c = sub * 6 + e;
    int f = c >> 4, d = c & 15;
    Ob[(((size_t)(b_ * NN + q0 + r)) * 3 + f) * 128 + h_ * 16 + d] = acc[e] * invl;
  }
}

// ---------------------------------------------------------------------------
// out: out = ev_nonlin(resi @ w_out). 8 tokens per block (128 threads).
// ---------------------------------------------------------------------------
__global__ __launch_bounds__(128) void out_kernel(
    const float* __restrict__ Ob, const float* __restrict__ w_out,
    const float* __restrict__ w1, const float* __restrict__ b1,
    const float* __restrict__ w2, const float* __restrict__ b2,
    float* __restrict__ out)
{
  const int t0 = blockIdx.x * TB;
  const int j = threadIdx.x;
  __shared__ float rs[TB][384];
  __shared__ float norm_s[TB][128];
  __shared__ float h_s[TB][64];

  {
    const float4* src = (const float4*)(Ob + (size_t)t0 * 384);
    float4* dst = (float4*)&rs[0][0];
    #pragma unroll
    for (int i = 0; i < 6; ++i) dst[j + i * 128] = src[j + i * 128];
  }
  __syncthreads();

  float p0[TB], p1[TB], p2[TB];
  #pragma unroll
  for (int t = 0; t < TB; ++t) { p0[t] = 0.f; p1[t] = 0.f; p2[t] = 0.f; }
  for (int c = 0; c < 128; ++c) {
    float wv = w_out[c * 128 + j];
    #pragma unroll
    for (int t = 0; t < TB; ++t) {
      p0[t] += rs[t][c] * wv; p1[t] += rs[t][128 + c] * wv; p2[t] += rs[t][256 + c] * wv;
    }
  }
  float np[TB]; int zmask = 0;
  #pragma unroll
  for (int t = 0; t < TB; ++t) {
    float nn = sqrtf(p0[t] * p0[t] + p1[t] * p1[t] + p2[t] * p2[t]);
    if (nn <= EPSV) zmask |= (1 << t);
    np[t] = nn + EPSV;
    norm_s[t][j] = np[t];
  }
  __syncthreads();

  {
    const int jc = j & 63;
    const int tb = (j >> 6) * 4;
    float a0 = b1[jc], a1 = a0, a2 = a0, a3 = a0;
    for (int c = 0; c < 128; ++c) {
      float wv = w1[c * 64 + jc];
      a0 += norm_s[tb + 0][c] * wv; a1 += norm_s[tb + 1][c] * wv;
      a2 += norm_s[tb + 2][c] * wv; a3 += norm_s[tb + 3][c] * wv;
    }
    h_s[tb + 0][jc] = a0 > 0.f ? a0 : NSL * a0;
    h_s[tb + 1][jc] = a1 > 0.f ? a1 : NSL * a1;
    h_s[tb + 2][jc] = a2 > 0.f ? a2 : NSL * a2;
    h_s[tb + 3][jc] = a3 > 0.f ? a3 : NSL * a3;
  }
  __syncthreads();

  float bn[TB];
  {
    float b2j = b2[j];
    #pragma unroll
    for (int t = 0; t < TB; ++t) bn[t] = b2j + np[t];
    for (int i = 0; i < 64; ++i) {
      float wv = w2[i * 128 + j];
      #pragma unroll
      for (int t = 0; t < TB; ++t) bn[t] += h_s[t][i] * wv;
    }
  }
  #pragma unroll
  for (int t = 0; t < TB; ++t) {
    float ratio = (zmask >> t) & 1 ? 1.f : bn[t] / np[t];
    float* od = out + (size_t)(t0 + t) * 384;
    od[j] = p0[t] * ratio; od[128 + j] = p1[t] * ratio; od[256 + j] = p2[t] * ratio;
  }
}

// ---------------------------------------------------------------------------
extern "C" void kernel_launch(void* const* d_in, const int* in_sizes, int n_in,
                              void* d_out, int out_size, void* d_ws, size_t ws_size,
                              hipStream_t stream) {
  const float* qfts   = (const float*)d_in[0];
  const float* kvfts  = (const float*)d_in[1];
  const float* w_q_in = (const float*)d_in[2];
  const float* q_w1   = (const float*)d_in[3];
  const float* q_b1   = (const float*)d_in[4];
  const float* q_w2   = (const float*)d_in[5];
  const float* q_b2   = (const float*)d_in[6];
  const float* w_kv_in= (const float*)d_in[7];
  const float* kv_w1  = (const float*)d_in[8];
  const float* kv_b1  = (const float*)d_in[9];
  const float* kv_w2  = (const float*)d_in[10];
  const float* kv_b2  = (const float*)d_in[11];
  const float* w_q    = (const float*)d_in[12];
  const float* w_k    = (const float*)d_in[13];
  const float* w_v    = (const float*)d_in[14];
  const float* w_out  = (const float*)d_in[15];
  const float* o_w1   = (const float*)d_in[16];
  const float* o_b1   = (const float*)d_in[17];
  const float* o_w2   = (const float*)d_in[18];
  const float* o_b2   = (const float*)d_in[19];

  const size_t per = (size_t)HH * BB * NN * 48;
  float* Qbuf = (float*)d_ws;
  float* Kbuf = Qbuf + per;
  float* Vbuf = Kbuf + per;
  float* Obuf = Vbuf + per;

  pre_q_kernel<<<BB * NN / TB, 128, 0, stream>>>(qfts, w_q_in, q_w1, q_b1, q_w2, q_b2, w_q, Qbuf);
  pre_kv_kernel<<<BB * NN / TB, 128, 0, stream>>>(kvfts, w_kv_in, kv_w1, kv_b1, kv_w2, kv_b2,
                                                  w_k, w_v, Kbuf, Vbuf);
  dim3 ag(NN / QT, HH * BB);
  attn_kernel<<<ag, 256, 0, stream>>>(Qbuf, Kbuf, Vbuf, Obuf);
  out_kernel<<<BB * NN / TB, 128, 0, stream>>>(Obuf, w_out, o_w1, o_b1, o_w2, o_b2, (float*)d_out);
}

// Round 3
// 208.845 us; speedup vs baseline: 2.6586x; 2.6431x over previous
//
#include <hip/hip_runtime.h>
#include <math.h>

#define EPSV 1e-6f
#define NSL  0.2f
#define BB   2
#define NN   2048
#define HH   8
#define TB   4     // tokens per block in pre/out kernels

typedef short bf16x8 __attribute__((ext_vector_type(8)));
typedef float f32x4  __attribute__((ext_vector_type(4)));

__device__ __forceinline__ unsigned short f2bf(float x) {
  union { float f; unsigned int u; } v; v.f = x;
  unsigned int r = v.u + 0x7FFF + ((v.u >> 16) & 1);
  return (unsigned short)(r >> 16);
}
__device__ __forceinline__ float bf2f(unsigned short h) {
  union { float f; unsigned int u; } v; v.u = ((unsigned int)h) << 16;
  return v.f;
}

// Workspace fragment layouts (all bf16 hi/lo planes):
// QW/KW: per (hb, tile16): [hl 2][768]:  c0 = [lane 64][8] at 0, c1 = [lane<32][8] at 512.
//   element(c0): row=lane&15 (q/k within tile), d = (lane>>4)*8 + j
//   element(c1): d = 32 + (lane>>4)*8 + j   (only lanes<32 valid; rest is pad-read)
// VW: per (hb, kc32, f): [hl 2][512]: [lane 64][8]
//   element: d_row = f*16 + (lane&15), k = kc*32 + (lane>>4)*8 + j

// ---------------------------------------------------------------------------
// pre_q
// ---------------------------------------------------------------------------
__global__ __launch_bounds__(128) void pre_q_kernel(
    const float* __restrict__ x_in, const float* __restrict__ w_in,
    const float* __restrict__ w1, const float* __restrict__ b1,
    const float* __restrict__ w2, const float* __restrict__ b2,
    const float* __restrict__ w_h, unsigned short* __restrict__ QW)
{
  const int t0 = blockIdx.x * TB;
  const int j = threadIdx.x;
  __shared__ float xs[TB][192];
  __shared__ float norm_s[TB][128];
  __shared__ float h_s[TB][64];
  __shared__ float qf_s[TB][3][128];

  {
    const float4* src = (const float4*)(x_in + (size_t)t0 * 192);
    float4* dst = (float4*)&xs[0][0];
    dst[j] = src[j];
    if (j < 64) dst[128 + j] = src[128 + j];
  }
  __syncthreads();

  float p0[TB], p1[TB], p2[TB];
  #pragma unroll
  for (int t = 0; t < TB; ++t) { p0[t] = 0.f; p1[t] = 0.f; p2[t] = 0.f; }
  for (int c = 0; c < 64; ++c) {
    float wv = w_in[c * 128 + j];
    #pragma unroll
    for (int t = 0; t < TB; ++t) {
      p0[t] += xs[t][c] * wv; p1[t] += xs[t][64 + c] * wv; p2[t] += xs[t][128 + c] * wv;
    }
  }
  float np[TB]; int zmask = 0;
  #pragma unroll
  for (int t = 0; t < TB; ++t) {
    float nn = sqrtf(p0[t] * p0[t] + p1[t] * p1[t] + p2[t] * p2[t]);
    if (nn <= EPSV) zmask |= (1 << t);
    np[t] = nn + EPSV;
    norm_s[t][j] = np[t];
  }
  __syncthreads();

  {
    const int jc = j & 63;
    const int tb = (j >> 6) * 2;
    float a0 = b1[jc], a1 = a0;
    for (int c = 0; c < 128; ++c) {
      float wv = w1[c * 64 + jc];
      a0 += norm_s[tb + 0][c] * wv; a1 += norm_s[tb + 1][c] * wv;
    }
    h_s[tb + 0][jc] = a0 > 0.f ? a0 : NSL * a0;
    h_s[tb + 1][jc] = a1 > 0.f ? a1 : NSL * a1;
  }
  __syncthreads();

  float bn[TB];
  {
    float b2j = b2[j];
    #pragma unroll
    for (int t = 0; t < TB; ++t) bn[t] = b2j + np[t];
    for (int i = 0; i < 64; ++i) {
      float wv = w2[i * 128 + j];
      #pragma unroll
      for (int t = 0; t < TB; ++t) bn[t] += h_s[t][i] * wv;
    }
  }
  #pragma unroll
  for (int t = 0; t < TB; ++t) {
    float ratio = (zmask >> t) & 1 ? 1.f : bn[t] / np[t];
    qf_s[t][0][j] = p0[t] * ratio; qf_s[t][1][j] = p1[t] * ratio; qf_s[t][2][j] = p2[t] * ratio;
  }
  __syncthreads();

  float q0[TB], q1[TB], q2[TB];
  #pragma unroll
  for (int t = 0; t < TB; ++t) { q0[t] = 0.f; q1[t] = 0.f; q2[t] = 0.f; }
  for (int c = 0; c < 128; ++c) {
    float wv = w_h[c * 128 + j];
    #pragma unroll
    for (int t = 0; t < TB; ++t) {
      q0[t] += qf_s[t][0][c] * wv; q1[t] += qf_s[t][1][c] * wv; q2[t] += qf_s[t][2][c] * wv;
    }
  }
  const int hh = j >> 4, dd = j & 15;
  #pragma unroll
  for (int t = 0; t < TB; ++t) {
    float ss = q0[t] * q0[t] + q1[t] * q1[t] + q2[t] * q2[t];
    ss += __shfl_xor(ss, 1, 16);
    ss += __shfl_xor(ss, 2, 16);
    ss += __shfl_xor(ss, 4, 16);
    ss += __shfl_xor(ss, 8, 16);
    float inv = 0.25f / (sqrtf(ss * (1.f / 16.f)) + EPSV);   // fold 1/sqrt(hd) scale
    const int tok = t0 + t;
    const int b = tok >> 11, n = tok & (NN - 1);
    const int hb = hh * BB + b;
    const size_t base = (size_t)(hb * 128 + (n >> 4)) * 1536;
    const int row = n & 15;
    float vals[3] = {q0[t] * inv, q1[t] * inv, q2[t] * inv};
    #pragma unroll
    for (int f = 0; f < 3; ++f) {
      int d = f * 16 + dd;
      int off;
      if (d < 32) off = ((d >> 3) * 16 + row) * 8 + (d & 7);
      else        off = 512 + (((d - 32) >> 3) * 16 + row) * 8 + ((d - 32) & 7);
      unsigned short hi = f2bf(vals[f]);
      QW[base + off] = hi;
      QW[base + 768 + off] = f2bf(vals[f] - bf2f(hi));
    }
  }
}

// ---------------------------------------------------------------------------
// pre_kv
// ---------------------------------------------------------------------------
__global__ __launch_bounds__(128) void pre_kv_kernel(
    const float* __restrict__ x_in, const float* __restrict__ w_in,
    const float* __restrict__ w1, const float* __restrict__ b1,
    const float* __restrict__ w2, const float* __restrict__ b2,
    const float* __restrict__ w_k, const float* __restrict__ w_v,
    unsigned short* __restrict__ KW, unsigned short* __restrict__ VW)
{
  const int t0 = blockIdx.x * TB;
  const int j = threadIdx.x;
  __shared__ float xs[TB][192];
  __shared__ float norm_s[TB][128];
  __shared__ float h_s[TB][64];
  __shared__ float kf_s[TB][3][128];

  {
    const float4* src = (const float4*)(x_in + (size_t)t0 * 192);
    float4* dst = (float4*)&xs[0][0];
    dst[j] = src[j];
    if (j < 64) dst[128 + j] = src[128 + j];
  }
  __syncthreads();

  float p0[TB], p1[TB], p2[TB];
  #pragma unroll
  for (int t = 0; t < TB; ++t) { p0[t] = 0.f; p1[t] = 0.f; p2[t] = 0.f; }
  for (int c = 0; c < 64; ++c) {
    float wv = w_in[c * 128 + j];
    #pragma unroll
    for (int t = 0; t < TB; ++t) {
      p0[t] += xs[t][c] * wv; p1[t] += xs[t][64 + c] * wv; p2[t] += xs[t][128 + c] * wv;
    }
  }
  float np[TB]; int zmask = 0;
  #pragma unroll
  for (int t = 0; t < TB; ++t) {
    float nn = sqrtf(p0[t] * p0[t] + p1[t] * p1[t] + p2[t] * p2[t]);
    if (nn <= EPSV) zmask |= (1 << t);
    np[t] = nn + EPSV;
    norm_s[t][j] = np[t];
  }
  __syncthreads();

  {
    const int jc = j & 63;
    const int tb = (j >> 6) * 2;
    float a0 = b1[jc], a1 = a0;
    for (int c = 0; c < 128; ++c) {
      float wv = w1[c * 64 + jc];
      a0 += norm_s[tb + 0][c] * wv; a1 += norm_s[tb + 1][c] * wv;
    }
    h_s[tb + 0][jc] = a0 > 0.f ? a0 : NSL * a0;
    h_s[tb + 1][jc] = a1 > 0.f ? a1 : NSL * a1;
  }
  __syncthreads();

  float bn[TB];
  {
    float b2j = b2[j];
    #pragma unroll
    for (int t = 0; t < TB; ++t) bn[t] = b2j + np[t];
    for (int i = 0; i < 64; ++i) {
      float wv = w2[i * 128 + j];
      #pragma unroll
      for (int t = 0; t < TB; ++t) bn[t] += h_s[t][i] * wv;
    }
  }
  #pragma unroll
  for (int t = 0; t < TB; ++t) {
    float ratio = (zmask >> t) & 1 ? 1.f : bn[t] / np[t];
    kf_s[t][0][j] = p0[t] * ratio; kf_s[t][1][j] = p1[t] * ratio; kf_s[t][2][j] = p2[t] * ratio;
  }
  __syncthreads();

  const int hh = j >> 4, dd = j & 15;

  // K projection + layernorm -> KW frags
  {
    float q0[TB], q1[TB], q2[TB];
    #pragma unroll
    for (int t = 0; t < TB; ++t) { q0[t] = 0.f; q1[t] = 0.f; q2[t] = 0.f; }
    for (int c = 0; c < 128; ++c) {
      float wv = w_k[c * 128 + j];
      #pragma unroll
      for (int t = 0; t < TB; ++t) {
        q0[t] += kf_s[t][0][c] * wv; q1[t] += kf_s[t][1][c] * wv; q2[t] += kf_s[t][2][c] * wv;
      }
    }
    #pragma unroll
    for (int t = 0; t < TB; ++t) {
      float ss = q0[t] * q0[t] + q1[t] * q1[t] + q2[t] * q2[t];
      ss += __shfl_xor(ss, 1, 16);
      ss += __shfl_xor(ss, 2, 16);
      ss += __shfl_xor(ss, 4, 16);
      ss += __shfl_xor(ss, 8, 16);
      float inv = 1.f / (sqrtf(ss * (1.f / 16.f)) + EPSV);
      const int tok = t0 + t;
      const int b = tok >> 11, n = tok & (NN - 1);
      const int hb = hh * BB + b;
      const size_t base = (size_t)(hb * 128 + (n >> 4)) * 1536;
      const int row = n & 15;
      float vals[3] = {q0[t] * inv, q1[t] * inv, q2[t] * inv};
      #pragma unroll
      for (int f = 0; f < 3; ++f) {
        int d = f * 16 + dd;
        int off;
        if (d < 32) off = ((d >> 3) * 16 + row) * 8 + (d & 7);
        else        off = 512 + (((d - 32) >> 3) * 16 + row) * 8 + ((d - 32) & 7);
        unsigned short hi = f2bf(vals[f]);
        KW[base + off] = hi;
        KW[base + 768 + off] = f2bf(vals[f] - bf2f(hi));
      }
    }
  }
  // V projection -> VW frags (V^T layout)
  {
    float v0[TB], v1[TB], v2[TB];
    #pragma unroll
    for (int t = 0; t < TB; ++t) { v0[t] = 0.f; v1[t] = 0.f; v2[t] = 0.f; }
    for (int c = 0; c < 128; ++c) {
      float wv = w_v[c * 128 + j];
      #pragma unroll
      for (int t = 0; t < TB; ++t) {
        v0[t] += kf_s[t][0][c] * wv; v1[t] += kf_s[t][1][c] * wv; v2[t] += kf_s[t][2][c] * wv;
      }
    }
    #pragma unroll
    for (int t = 0; t < TB; ++t) {
      const int tok = t0 + t;
      const int b = tok >> 11, n = tok & (NN - 1);
      const int hb = hh * BB + b;
      const int off = (((n & 31) >> 3) * 16 + dd) * 8 + (n & 7);
      float vals[3] = {v0[t], v1[t], v2[t]};
      #pragma unroll
      for (int f = 0; f < 3; ++f) {
        const size_t vbase = (size_t)((hb * 64 + (n >> 5)) * 3 + f) * 1024;
        unsigned short hi = f2bf(vals[f]);
        VW[vbase + off] = hi;
        VW[vbase + 512 + off] = f2bf(vals[f] - bf2f(hi));
      }
    }
  }
}

// ---------------------------------------------------------------------------
// attention: MFMA flash. 4 independent waves/block, 16 q-rows per wave.
// S^T = K·Q^T (3-term hi/lo), online softmax in D-layout regs,
// P routed through per-wave LDS (write b64, read b128), O^T = V^T·P (3-term).
// ---------------------------------------------------------------------------
__global__ __launch_bounds__(256) void attn_kernel(
    const unsigned short* __restrict__ QW, const unsigned short* __restrict__ KW,
    const unsigned short* __restrict__ VW, float* __restrict__ Ob)
{
  const int lane = threadIdx.x & 63;
  const int w = threadIdx.x >> 6;
  const int hb = blockIdx.y;
  const int t = blockIdx.x * 4 + w;
  const int q = lane & 15, g = lane >> 4;

  __shared__ unsigned short plds[4][2][1152];   // per wave: [hl][16 q][72]

  // Q B-frags (hoisted): c0 full, c1 zero for lanes>=32 (covers d=48..63 pad)
  const size_t qbase = (size_t)(hb * 128 + t) * 1536;
  bf16x8 qh0 = *(const bf16x8*)(QW + qbase + lane * 8);
  bf16x8 ql0 = *(const bf16x8*)(QW + qbase + 768 + lane * 8);
  bf16x8 qh1 = {0, 0, 0, 0, 0, 0, 0, 0};
  bf16x8 ql1 = {0, 0, 0, 0, 0, 0, 0, 0};
  if (lane < 32) {
    qh1 = *(const bf16x8*)(QW + qbase + 512 + lane * 8);
    ql1 = *(const bf16x8*)(QW + qbase + 768 + 512 + lane * 8);
  }

  f32x4 o[3];
  #pragma unroll
  for (int f = 0; f < 3; ++f) o[f] = (f32x4){0.f, 0.f, 0.f, 0.f};
  float m = -INFINITY, lsum = 0.f;

  for (int T = 0; T < 32; ++T) {
    // ---- S^T tiles: 4 subtiles of 16 k ----
    f32x4 sc[4];
    #pragma unroll
    for (int st = 0; st < 4; ++st) {
      const size_t kb = (size_t)(hb * 128 + T * 4 + st) * 1536;
      bf16x8 kh0 = *(const bf16x8*)(KW + kb + lane * 8);
      bf16x8 kl0 = *(const bf16x8*)(KW + kb + 768 + lane * 8);
      bf16x8 kh1 = *(const bf16x8*)(KW + kb + 512 + lane * 8);
      bf16x8 kl1 = *(const bf16x8*)(KW + kb + 768 + 512 + lane * 8);
      f32x4 a = {0.f, 0.f, 0.f, 0.f};
      a = __builtin_amdgcn_mfma_f32_16x16x32_bf16(kh0, qh0, a, 0, 0, 0);
      a = __builtin_amdgcn_mfma_f32_16x16x32_bf16(kh0, ql0, a, 0, 0, 0);
      a = __builtin_amdgcn_mfma_f32_16x16x32_bf16(kl0, qh0, a, 0, 0, 0);
      a = __builtin_amdgcn_mfma_f32_16x16x32_bf16(kh1, qh1, a, 0, 0, 0);
      a = __builtin_amdgcn_mfma_f32_16x16x32_bf16(kh1, ql1, a, 0, 0, 0);
      a = __builtin_amdgcn_mfma_f32_16x16x32_bf16(kl1, qh1, a, 0, 0, 0);
      sc[st] = a;
    }

    // ---- online softmax (lane holds 16 scores for q-col, k = st*16+g*4+r) ----
    float tm = sc[0][0];
    #pragma unroll
    for (int st = 0; st < 4; ++st)
      #pragma unroll
      for (int r = 0; r < 4; ++r) tm = fmaxf(tm, sc[st][r]);
    tm = fmaxf(tm, __shfl_xor(tm, 16));
    tm = fmaxf(tm, __shfl_xor(tm, 32));
    float mnew = fmaxf(m, tm);
    float scale = __expf(m - mnew);
    lsum *= scale;
    #pragma unroll
    for (int f = 0; f < 3; ++f) {
      o[f][0] *= scale; o[f][1] *= scale; o[f][2] *= scale; o[f][3] *= scale;
    }
    float lp = 0.f;
    #pragma unroll
    for (int st = 0; st < 4; ++st) {
      float p0 = __expf(sc[st][0] - mnew);
      float p1 = __expf(sc[st][1] - mnew);
      float p2 = __expf(sc[st][2] - mnew);
      float p3 = __expf(sc[st][3] - mnew);
      lp += (p0 + p1) + (p2 + p3);
      unsigned short h0 = f2bf(p0), h1 = f2bf(p1), h2 = f2bf(p2), h3 = f2bf(p3);
      uint2 uh = {(unsigned)h0 | ((unsigned)h1 << 16), (unsigned)h2 | ((unsigned)h3 << 16)};
      unsigned short l0 = f2bf(p0 - bf2f(h0)), l1 = f2bf(p1 - bf2f(h1));
      unsigned short l2 = f2bf(p2 - bf2f(h2)), l3 = f2bf(p3 - bf2f(h3));
      uint2 ul = {(unsigned)l0 | ((unsigned)l1 << 16), (unsigned)l2 | ((unsigned)l3 << 16)};
      *(uint2*)&plds[w][0][q * 72 + st * 16 + g * 4] = uh;
      *(uint2*)&plds[w][1][q * 72 + st * 16 + g * 4] = ul;
    }
    lp += __shfl_xor(lp, 16);
    lp += __shfl_xor(lp, 32);
    lsum += lp;
    m = mnew;

    asm volatile("s_waitcnt lgkmcnt(0)" ::: "memory");

    // ---- PV: O^T += V^T · P over the two 32-k chunks ----
    #pragma unroll
    for (int c = 0; c < 2; ++c) {
      const int kc = T * 2 + c;
      bf16x8 pbh = *(const bf16x8*)&plds[w][0][q * 72 + c * 32 + g * 8];
      bf16x8 pbl = *(const bf16x8*)&plds[w][1][q * 72 + c * 32 + g * 8];
      #pragma unroll
      for (int f = 0; f < 3; ++f) {
        const size_t vb = (size_t)((hb * 64 + kc) * 3 + f) * 1024;
        bf16x8 vh = *(const bf16x8*)(VW + vb + lane * 8);
        bf16x8 vl = *(const bf16x8*)(VW + vb + 512 + lane * 8);
        o[f] = __builtin_amdgcn_mfma_f32_16x16x32_bf16(vh, pbh, o[f], 0, 0, 0);
        o[f] = __builtin_amdgcn_mfma_f32_16x16x32_bf16(vh, pbl, o[f], 0, 0, 0);
        o[f] = __builtin_amdgcn_mfma_f32_16x16x32_bf16(vl, pbh, o[f], 0, 0, 0);
      }
    }
  }

  const float invl = 1.f / lsum;
  const int h_ = hb >> 1, b_ = hb & 1;
  const int n = t * 16 + q;
  #pragma unroll
  for (int f = 0; f < 3; ++f) {
    float4 st4 = {o[f][0] * invl, o[f][1] * invl, o[f][2] * invl, o[f][3] * invl};
    *(float4*)&Ob[(((size_t)(b_ * NN + n)) * 3 + f) * 128 + h_ * 16 + g * 4] = st4;
  }
}

// ---------------------------------------------------------------------------
// out: out = ev_nonlin(resi @ w_out). TB tokens per block (128 threads).
// ---------------------------------------------------------------------------
__global__ __launch_bounds__(128) void out_kernel(
    const float* __restrict__ Ob, const float* __restrict__ w_out,
    const float* __restrict__ w1, const float* __restrict__ b1,
    const float* __restrict__ w2, const float* __restrict__ b2,
    float* __restrict__ out)
{
  const int t0 = blockIdx.x * TB;
  const int j = threadIdx.x;
  __shared__ float rs[TB][384];
  __shared__ float norm_s[TB][128];
  __shared__ float h_s[TB][64];

  {
    const float4* src = (const float4*)(Ob + (size_t)t0 * 384);
    float4* dst = (float4*)&rs[0][0];
    #pragma unroll
    for (int i = 0; i < 3; ++i) dst[j + i * 128] = src[j + i * 128];
  }
  __syncthreads();

  float p0[TB], p1[TB], p2[TB];
  #pragma unroll
  for (int t = 0; t < TB; ++t) { p0[t] = 0.f; p1[t] = 0.f; p2[t] = 0.f; }
  for (int c = 0; c < 128; ++c) {
    float wv = w_out[c * 128 + j];
    #pragma unroll
    for (int t = 0; t < TB; ++t) {
      p0[t] += rs[t][c] * wv; p1[t] += rs[t][128 + c] * wv; p2[t] += rs[t][256 + c] * wv;
    }
  }
  float np[TB]; int zmask = 0;
  #pragma unroll
  for (int t = 0; t < TB; ++t) {
    float nn = sqrtf(p0[t] * p0[t] + p1[t] * p1[t] + p2[t] * p2[t]);
    if (nn <= EPSV) zmask |= (1 << t);
    np[t] = nn + EPSV;
    norm_s[t][j] = np[t];
  }
  __syncthreads();

  {
    const int jc = j & 63;
    const int tb = (j >> 6) * 2;
    float a0 = b1[jc], a1 = a0;
    for (int c = 0; c < 128; ++c) {
      float wv = w1[c * 64 + jc];
      a0 += norm_s[tb + 0][c] * wv; a1 += norm_s[tb + 1][c] * wv;
    }
    h_s[tb + 0][jc] = a0 > 0.f ? a0 : NSL * a0;
    h_s[tb + 1][jc] = a1 > 0.f ? a1 : NSL * a1;
  }
  __syncthreads();

  float bn[TB];
  {
    float b2j = b2[j];
    #pragma unroll
    for (int t = 0; t < TB; ++t) bn[t] = b2j + np[t];
    for (int i = 0; i < 64; ++i) {
      float wv = w2[i * 128 + j];
      #pragma unroll
      for (int t = 0; t < TB; ++t) bn[t] += h_s[t][i] * wv;
    }
  }
  #pragma unroll
  for (int t = 0; t < TB; ++t) {
    float ratio = (zmask >> t) & 1 ? 1.f : bn[t] / np[t];
    float* od = out + (size_t)(t0 + t) * 384;
    od[j] = p0[t] * ratio; od[128 + j] = p1[t] * ratio; od[256 + j] = p2[t] * ratio;
  }
}

// ---------------------------------------------------------------------------
extern "C" void kernel_launch(void* const* d_in, const int* in_sizes, int n_in,
                              void* d_out, int out_size, void* d_ws, size_t ws_size,
                              hipStream_t stream) {
  const float* qfts   = (const float*)d_in[0];
  const float* kvfts  = (const float*)d_in[1];
  const float* w_q_in = (const float*)d_in[2];
  const float* q_w1   = (const float*)d_in[3];
  const float* q_b1   = (const float*)d_in[4];
  const float* q_w2   = (const float*)d_in[5];
  const float* q_b2   = (const float*)d_in[6];
  const float* w_kv_in= (const float*)d_in[7];
  const float* kv_w1  = (const float*)d_in[8];
  const float* kv_b1  = (const float*)d_in[9];
  const float* kv_w2  = (const float*)d_in[10];
  const float* kv_b2  = (const float*)d_in[11];
  const float* w_q    = (const float*)d_in[12];
  const float* w_k    = (const float*)d_in[13];
  const float* w_v    = (const float*)d_in[14];
  const float* w_out  = (const float*)d_in[15];
  const float* o_w1   = (const float*)d_in[16];
  const float* o_b1   = (const float*)d_in[17];
  const float* o_w2   = (const float*)d_in[18];
  const float* o_b2   = (const float*)d_in[19];

  // ws carve (bytes): QW 6.29MB | KW 6.29MB | VW 6.29MB | Obuf 6.29MB = 25.2MB
  unsigned short* QW = (unsigned short*)d_ws;
  unsigned short* KW = QW + 3145728;
  unsigned short* VW = KW + 3145728;
  float* Obuf = (float*)(VW + 3145728);

  pre_q_kernel<<<BB * NN / TB, 128, 0, stream>>>(qfts, w_q_in, q_w1, q_b1, q_w2, q_b2, w_q, QW);
  pre_kv_kernel<<<BB * NN / TB, 128, 0, stream>>>(kvfts, w_kv_in, kv_w1, kv_b1, kv_w2, kv_b2,
                                                  w_k, w_v, KW, VW);
  dim3 ag(32, 16);
  attn_kernel<<<ag, 256, 0, stream>>>(QW, KW, VW, Obuf);
  out_kernel<<<BB * NN / TB, 128, 0, stream>>>(Obuf, w_out, o_w1, o_b1, o_w2, o_b2, (float*)d_out);
}

// Round 4
// 185.505 us; speedup vs baseline: 2.9931x; 1.1258x over previous
//
#include <hip/hip_runtime.h>
#include <math.h>

#define EPSV 1e-6f
#define NSL  0.2f
#define BB   2
#define NN   2048
#define HH   8
#define TB   8

typedef short bf16x8 __attribute__((ext_vector_type(8)));
typedef float f32x4  __attribute__((ext_vector_type(4)));

__device__ __forceinline__ unsigned short f2bf(float x) {
  union { float f; unsigned int u; } v; v.f = x;
  unsigned int r = v.u + 0x7FFF + ((v.u >> 16) & 1);
  return (unsigned short)(r >> 16);
}
__device__ __forceinline__ float bf2f(unsigned short h) {
  union { float f; unsigned int u; } v; v.u = ((unsigned int)h) << 16;
  return v.f;
}

// Workspace fragment layouts (bf16 hi/lo planes) — same as round 3:
// QW/KW per (hb, tile16): [hl 2][768]: c0=[lane64][8] @0, c1=[lane<32][8] @512
// VW per (hb, kc32, f):   [hl 2][512]: [lane64][8]

// ---------------------------------------------------------------------------
// pre: merged q/kv branch (blockIdx.y: 0=q, 1=kv). 8 tokens / 128 threads.
// Vectorized: LDS operands via broadcast float4, weight loops step 4.
// ---------------------------------------------------------------------------
__global__ __launch_bounds__(128) void pre_kernel(
    const float* __restrict__ qfts, const float* __restrict__ kvfts,
    const float* __restrict__ wq_in, const float* __restrict__ qw1, const float* __restrict__ qb1,
    const float* __restrict__ qw2, const float* __restrict__ qb2,
    const float* __restrict__ wkv_in, const float* __restrict__ kw1, const float* __restrict__ kb1,
    const float* __restrict__ kw2, const float* __restrict__ kb2,
    const float* __restrict__ w_q, const float* __restrict__ w_k, const float* __restrict__ w_v,
    unsigned short* __restrict__ QW, unsigned short* __restrict__ KW, unsigned short* __restrict__ VW)
{
  const bool is_kv = blockIdx.y != 0;
  const float* x_in = is_kv ? kvfts : qfts;
  const float* w_in = is_kv ? wkv_in : wq_in;
  const float* w1   = is_kv ? kw1 : qw1;
  const float* b1   = is_kv ? kb1 : qb1;
  const float* w2   = is_kv ? kw2 : qw2;
  const float* b2   = is_kv ? kb2 : qb2;
  const float* w_p  = is_kv ? w_k : w_q;
  unsigned short* FW = is_kv ? KW : QW;
  const float ln_sc = is_kv ? 1.f : 0.25f;   // fold 1/sqrt(hd) into Q

  const int t0 = blockIdx.x * TB;
  const int j = threadIdx.x;
  __shared__ float xs[TB][192];
  __shared__ float norm_s[TB][128];
  __shared__ float h_s[TB][64];
  __shared__ float f_s[TB][3][128];

  {
    const float4* src = (const float4*)(x_in + (size_t)t0 * 192);
    float4* dst = (float4*)&xs[0][0];
    #pragma unroll
    for (int i = 0; i < 3; ++i) dst[j + i * 128] = src[j + i * 128];
  }
  __syncthreads();

  float p0[TB], p1[TB], p2[TB];
  #pragma unroll
  for (int t = 0; t < TB; ++t) { p0[t] = 0.f; p1[t] = 0.f; p2[t] = 0.f; }
  #pragma unroll 2
  for (int c = 0; c < 64; c += 4) {
    float w4[4];
    #pragma unroll
    for (int i = 0; i < 4; ++i) w4[i] = w_in[(c + i) * 128 + j];
    #pragma unroll
    for (int t = 0; t < TB; ++t) {
      float4 x0 = *(const float4*)&xs[t][c];
      float4 x1 = *(const float4*)&xs[t][64 + c];
      float4 x2 = *(const float4*)&xs[t][128 + c];
      p0[t] += x0.x * w4[0] + x0.y * w4[1] + x0.z * w4[2] + x0.w * w4[3];
      p1[t] += x1.x * w4[0] + x1.y * w4[1] + x1.z * w4[2] + x1.w * w4[3];
      p2[t] += x2.x * w4[0] + x2.y * w4[1] + x2.z * w4[2] + x2.w * w4[3];
    }
  }
  float np[TB]; int zmask = 0;
  #pragma unroll
  for (int t = 0; t < TB; ++t) {
    float nn = sqrtf(p0[t] * p0[t] + p1[t] * p1[t] + p2[t] * p2[t]);
    if (nn <= EPSV) zmask |= (1 << t);
    np[t] = nn + EPSV;
    norm_s[t][j] = np[t];
  }
  __syncthreads();

  {
    const int jc = j & 63;
    const int tb = (j >> 6) * 4;
    float a[4];
    float bb1 = b1[jc];
    #pragma unroll
    for (int u = 0; u < 4; ++u) a[u] = bb1;
    #pragma unroll 2
    for (int c = 0; c < 128; c += 4) {
      float w4[4];
      #pragma unroll
      for (int i = 0; i < 4; ++i) w4[i] = w1[(c + i) * 64 + jc];
      #pragma unroll
      for (int u = 0; u < 4; ++u) {
        float4 n4 = *(const float4*)&norm_s[tb + u][c];
        a[u] += n4.x * w4[0] + n4.y * w4[1] + n4.z * w4[2] + n4.w * w4[3];
      }
    }
    #pragma unroll
    for (int u = 0; u < 4; ++u)
      h_s[tb + u][jc] = a[u] > 0.f ? a[u] : NSL * a[u];
  }
  __syncthreads();

  float bn[TB];
  {
    float b2j = b2[j];
    #pragma unroll
    for (int t = 0; t < TB; ++t) bn[t] = b2j + np[t];
    #pragma unroll 2
    for (int i = 0; i < 64; i += 4) {
      float w4[4];
      #pragma unroll
      for (int ii = 0; ii < 4; ++ii) w4[ii] = w2[(i + ii) * 128 + j];
      #pragma unroll
      for (int t = 0; t < TB; ++t) {
        float4 h4 = *(const float4*)&h_s[t][i];
        bn[t] += h4.x * w4[0] + h4.y * w4[1] + h4.z * w4[2] + h4.w * w4[3];
      }
    }
  }
  #pragma unroll
  for (int t = 0; t < TB; ++t) {
    float ratio = (zmask >> t) & 1 ? 1.f : bn[t] / np[t];
    f_s[t][0][j] = p0[t] * ratio; f_s[t][1][j] = p1[t] * ratio; f_s[t][2][j] = p2[t] * ratio;
  }
  __syncthreads();

  const int hh = j >> 4, dd = j & 15;

  // main projection (+ EV layernorm) -> FW (QW or KW)
  {
    float q0[TB], q1[TB], q2[TB];
    #pragma unroll
    for (int t = 0; t < TB; ++t) { q0[t] = 0.f; q1[t] = 0.f; q2[t] = 0.f; }
    #pragma unroll 2
    for (int c = 0; c < 128; c += 4) {
      float w4[4];
      #pragma unroll
      for (int i = 0; i < 4; ++i) w4[i] = w_p[(c + i) * 128 + j];
      #pragma unroll
      for (int t = 0; t < TB; ++t) {
        float4 f0 = *(const float4*)&f_s[t][0][c];
        float4 f1 = *(const float4*)&f_s[t][1][c];
        float4 f2 = *(const float4*)&f_s[t][2][c];
        q0[t] += f0.x * w4[0] + f0.y * w4[1] + f0.z * w4[2] + f0.w * w4[3];
        q1[t] += f1.x * w4[0] + f1.y * w4[1] + f1.z * w4[2] + f1.w * w4[3];
        q2[t] += f2.x * w4[0] + f2.y * w4[1] + f2.z * w4[2] + f2.w * w4[3];
      }
    }
    #pragma unroll
    for (int t = 0; t < TB; ++t) {
      float ss = q0[t] * q0[t] + q1[t] * q1[t] + q2[t] * q2[t];
      ss += __shfl_xor(ss, 1, 16);
      ss += __shfl_xor(ss, 2, 16);
      ss += __shfl_xor(ss, 4, 16);
      ss += __shfl_xor(ss, 8, 16);
      float inv = ln_sc / (sqrtf(ss * (1.f / 16.f)) + EPSV);
      const int tok = t0 + t;
      const int b = tok >> 11, n = tok & (NN - 1);
      const int hb = hh * BB + b;
      const size_t base = (size_t)(hb * 128 + (n >> 4)) * 1536;
      const int row = n & 15;
      float vals[3] = {q0[t] * inv, q1[t] * inv, q2[t] * inv};
      #pragma unroll
      for (int f = 0; f < 3; ++f) {
        int d = f * 16 + dd;
        int off;
        if (d < 32) off = ((d >> 3) * 16 + row) * 8 + (d & 7);
        else        off = 512 + (((d - 32) >> 3) * 16 + row) * 8 + ((d - 32) & 7);
        unsigned short hi = f2bf(vals[f]);
        FW[base + off] = hi;
        FW[base + 768 + off] = f2bf(vals[f] - bf2f(hi));
      }
    }
  }
  // V projection (kv branch only) -> VW
  if (is_kv) {
    float v0[TB], v1[TB], v2[TB];
    #pragma unroll
    for (int t = 0; t < TB; ++t) { v0[t] = 0.f; v1[t] = 0.f; v2[t] = 0.f; }
    #pragma unroll 2
    for (int c = 0; c < 128; c += 4) {
      float w4[4];
      #pragma unroll
      for (int i = 0; i < 4; ++i) w4[i] = w_v[(c + i) * 128 + j];
      #pragma unroll
      for (int t = 0; t < TB; ++t) {
        float4 f0 = *(const float4*)&f_s[t][0][c];
        float4 f1 = *(const float4*)&f_s[t][1][c];
        float4 f2 = *(const float4*)&f_s[t][2][c];
        v0[t] += f0.x * w4[0] + f0.y * w4[1] + f0.z * w4[2] + f0.w * w4[3];
        v1[t] += f1.x * w4[0] + f1.y * w4[1] + f1.z * w4[2] + f1.w * w4[3];
        v2[t] += f2.x * w4[0] + f2.y * w4[1] + f2.z * w4[2] + f2.w * w4[3];
      }
    }
    #pragma unroll
    for (int t = 0; t < TB; ++t) {
      const int tok = t0 + t;
      const int b = tok >> 11, n = tok & (NN - 1);
      const int hb = hh * BB + b;
      const int off = (((n & 31) >> 3) * 16 + dd) * 8 + (n & 7);
      float vals[3] = {v0[t], v1[t], v2[t]};
      #pragma unroll
      for (int f = 0; f < 3; ++f) {
        const size_t vbase = (size_t)((hb * 64 + (n >> 5)) * 3 + f) * 1024;
        unsigned short hi = f2bf(vals[f]);
        VW[vbase + off] = hi;
        VW[vbase + 512 + off] = f2bf(vals[f] - bf2f(hi));
      }
    }
  }
}

// ---------------------------------------------------------------------------
// attention: MFMA flash, K-split over 2 wave groups.
// 512 threads = 8 waves: qt = w&3 (q-tile), kh = w>>2 (key half of 1024).
// Per-wave online softmax; halves merged through LDS at the end.
// ---------------------------------------------------------------------------
__global__ __launch_bounds__(512) void attn_kernel(
    const unsigned short* __restrict__ QW, const unsigned short* __restrict__ KW,
    const unsigned short* __restrict__ VW, float* __restrict__ Ob)
{
  const int lane = threadIdx.x & 63;
  const int w = threadIdx.x >> 6;
  const int qt = w & 3;
  const int kh = w >> 2;
  const int hb = blockIdx.y;
  const int t = blockIdx.x * 4 + qt;
  const int q = lane & 15, g = lane >> 4;

  __shared__ unsigned short plds[8][2][1152];   // per wave: [hl][16 q][72]
  __shared__ float comb[4][64][14];             // [qt][lane][o12, m, l]

  const size_t qbase = (size_t)(hb * 128 + t) * 1536;
  bf16x8 qh0 = *(const bf16x8*)(QW + qbase + lane * 8);
  bf16x8 ql0 = *(const bf16x8*)(QW + qbase + 768 + lane * 8);
  bf16x8 qh1 = {0, 0, 0, 0, 0, 0, 0, 0};
  bf16x8 ql1 = {0, 0, 0, 0, 0, 0, 0, 0};
  if (lane < 32) {
    qh1 = *(const bf16x8*)(QW + qbase + 512 + lane * 8);
    ql1 = *(const bf16x8*)(QW + qbase + 768 + 512 + lane * 8);
  }

  f32x4 o[3];
  #pragma unroll
  for (int f = 0; f < 3; ++f) o[f] = (f32x4){0.f, 0.f, 0.f, 0.f};
  float m = -INFINITY, lsum = 0.f;

  for (int T = kh * 16; T < kh * 16 + 16; ++T) {
    f32x4 sc[4];
    __builtin_amdgcn_s_setprio(1);
    #pragma unroll
    for (int st = 0; st < 4; ++st) {
      const size_t kb = (size_t)(hb * 128 + T * 4 + st) * 1536;
      bf16x8 kh0 = *(const bf16x8*)(KW + kb + lane * 8);
      bf16x8 kl0 = *(const bf16x8*)(KW + kb + 768 + lane * 8);
      bf16x8 kh1 = *(const bf16x8*)(KW + kb + 512 + lane * 8);
      bf16x8 kl1 = *(const bf16x8*)(KW + kb + 768 + 512 + lane * 8);
      f32x4 a = {0.f, 0.f, 0.f, 0.f};
      a = __builtin_amdgcn_mfma_f32_16x16x32_bf16(kh0, qh0, a, 0, 0, 0);
      a = __builtin_amdgcn_mfma_f32_16x16x32_bf16(kh0, ql0, a, 0, 0, 0);
      a = __builtin_amdgcn_mfma_f32_16x16x32_bf16(kl0, qh0, a, 0, 0, 0);
      a = __builtin_amdgcn_mfma_f32_16x16x32_bf16(kh1, qh1, a, 0, 0, 0);
      a = __builtin_amdgcn_mfma_f32_16x16x32_bf16(kh1, ql1, a, 0, 0, 0);
      a = __builtin_amdgcn_mfma_f32_16x16x32_bf16(kl1, qh1, a, 0, 0, 0);
      sc[st] = a;
    }
    __builtin_amdgcn_s_setprio(0);

    float tm = sc[0][0];
    #pragma unroll
    for (int st = 0; st < 4; ++st)
      #pragma unroll
      for (int r = 0; r < 4; ++r) tm = fmaxf(tm, sc[st][r]);
    tm = fmaxf(tm, __shfl_xor(tm, 16));
    tm = fmaxf(tm, __shfl_xor(tm, 32));
    float mnew = fmaxf(m, tm);
    float scale = __expf(m - mnew);
    lsum *= scale;
    #pragma unroll
    for (int f = 0; f < 3; ++f) {
      o[f][0] *= scale; o[f][1] *= scale; o[f][2] *= scale; o[f][3] *= scale;
    }
    float lp = 0.f;
    #pragma unroll
    for (int st = 0; st < 4; ++st) {
      float p0 = __expf(sc[st][0] - mnew);
      float p1 = __expf(sc[st][1] - mnew);
      float p2 = __expf(sc[st][2] - mnew);
      float p3 = __expf(sc[st][3] - mnew);
      lp += (p0 + p1) + (p2 + p3);
      unsigned short h0 = f2bf(p0), h1 = f2bf(p1), h2 = f2bf(p2), h3 = f2bf(p3);
      uint2 uh = {(unsigned)h0 | ((unsigned)h1 << 16), (unsigned)h2 | ((unsigned)h3 << 16)};
      unsigned short l0 = f2bf(p0 - bf2f(h0)), l1 = f2bf(p1 - bf2f(h1));
      unsigned short l2 = f2bf(p2 - bf2f(h2)), l3 = f2bf(p3 - bf2f(h3));
      uint2 ul = {(unsigned)l0 | ((unsigned)l1 << 16), (unsigned)l2 | ((unsigned)l3 << 16)};
      *(uint2*)&plds[w][0][q * 72 + st * 16 + g * 4] = uh;
      *(uint2*)&plds[w][1][q * 72 + st * 16 + g * 4] = ul;
    }
    lp += __shfl_xor(lp, 16);
    lp += __shfl_xor(lp, 32);
    lsum += lp;
    m = mnew;

    asm volatile("s_waitcnt lgkmcnt(0)" ::: "memory");

    __builtin_amdgcn_s_setprio(1);
    #pragma unroll
    for (int c = 0; c < 2; ++c) {
      const int kc = T * 2 + c;
      bf16x8 pbh = *(const bf16x8*)&plds[w][0][q * 72 + c * 32 + g * 8];
      bf16x8 pbl = *(const bf16x8*)&plds[w][1][q * 72 + c * 32 + g * 8];
      #pragma unroll
      for (int f = 0; f < 3; ++f) {
        const size_t vb = (size_t)((hb * 64 + kc) * 3 + f) * 1024;
        bf16x8 vh = *(const bf16x8*)(VW + vb + lane * 8);
        bf16x8 vl = *(const bf16x8*)(VW + vb + 512 + lane * 8);
        o[f] = __builtin_amdgcn_mfma_f32_16x16x32_bf16(vh, pbh, o[f], 0, 0, 0);
        o[f] = __builtin_amdgcn_mfma_f32_16x16x32_bf16(vh, pbl, o[f], 0, 0, 0);
        o[f] = __builtin_amdgcn_mfma_f32_16x16x32_bf16(vl, pbh, o[f], 0, 0, 0);
      }
    }
    __builtin_amdgcn_s_setprio(0);
  }

  // merge the two key-halves
  if (kh == 1) {
    float* cb = &comb[qt][lane][0];
    #pragma unroll
    for (int f = 0; f < 3; ++f)
      #pragma unroll
      for (int r = 0; r < 4; ++r) cb[f * 4 + r] = o[f][r];
    cb[12] = m; cb[13] = lsum;
  }
  __syncthreads();
  if (kh == 0) {
    const float* cb = &comb[qt][lane][0];
    float m1 = cb[12], l1 = cb[13];
    float mn = fmaxf(m, m1);
    float s0 = __expf(m - mn), s1 = __expf(m1 - mn);
    float invl = 1.f / (lsum * s0 + l1 * s1);
    const int h_ = hb >> 1, b_ = hb & 1;
    const int n = t * 16 + q;
    #pragma unroll
    for (int f = 0; f < 3; ++f) {
      float4 st4 = {(o[f][0] * s0 + cb[f * 4 + 0] * s1) * invl,
                    (o[f][1] * s0 + cb[f * 4 + 1] * s1) * invl,
                    (o[f][2] * s0 + cb[f * 4 + 2] * s1) * invl,
                    (o[f][3] * s0 + cb[f * 4 + 3] * s1) * invl};
      *(float4*)&Ob[(((size_t)(b_ * NN + n)) * 3 + f) * 128 + h_ * 16 + g * 4] = st4;
    }
  }
}

// ---------------------------------------------------------------------------
// out: out = ev_nonlin(resi @ w_out). 8 tokens / 128 threads, vectorized.
// ---------------------------------------------------------------------------
__global__ __launch_bounds__(128) void out_kernel(
    const float* __restrict__ Ob, const float* __restrict__ w_out,
    const float* __restrict__ w1, const float* __restrict__ b1,
    const float* __restrict__ w2, const float* __restrict__ b2,
    float* __restrict__ out)
{
  const int t0 = blockIdx.x * TB;
  const int j = threadIdx.x;
  __shared__ float rs[TB][384];
  __shared__ float norm_s[TB][128];
  __shared__ float h_s[TB][64];

  {
    const float4* src = (const float4*)(Ob + (size_t)t0 * 384);
    float4* dst = (float4*)&rs[0][0];
    #pragma unroll
    for (int i = 0; i < 6; ++i) dst[j + i * 128] = src[j + i * 128];
  }
  __syncthreads();

  float p0[TB], p1[TB], p2[TB];
  #pragma unroll
  for (int t = 0; t < TB; ++t) { p0[t] = 0.f; p1[t] = 0.f; p2[t] = 0.f; }
  #pragma unroll 2
  for (int c = 0; c < 128; c += 4) {
    float w4[4];
    #pragma unroll
    for (int i = 0; i < 4; ++i) w4[i] = w_out[(c + i) * 128 + j];
    #pragma unroll
    for (int t = 0; t < TB; ++t) {
      float4 x0 = *(const float4*)&rs[t][c];
      float4 x1 = *(const float4*)&rs[t][128 + c];
      float4 x2 = *(const float4*)&rs[t][256 + c];
      p0[t] += x0.x * w4[0] + x0.y * w4[1] + x0.z * w4[2] + x0.w * w4[3];
      p1[t] += x1.x * w4[0] + x1.y * w4[1] + x1.z * w4[2] + x1.w * w4[3];
      p2[t] += x2.x * w4[0] + x2.y * w4[1] + x2.z * w4[2] + x2.w * w4[3];
    }
  }
  float np[TB]; int zmask = 0;
  #pragma unroll
  for (int t = 0; t < TB; ++t) {
    float nn = sqrtf(p0[t] * p0[t] + p1[t] * p1[t] + p2[t] * p2[t]);
    if (nn <= EPSV) zmask |= (1 << t);
    np[t] = nn + EPSV;
    norm_s[t][j] = np[t];
  }
  __syncthreads();

  {
    const int jc = j & 63;
    const int tb = (j >> 6) * 4;
    float a[4];
    float bb1 = b1[jc];
    #pragma unroll
    for (int u = 0; u < 4; ++u) a[u] = bb1;
    #pragma unroll 2
    for (int c = 0; c < 128; c += 4) {
      float w4[4];
      #pragma unroll
      for (int i = 0; i < 4; ++i) w4[i] = w1[(c + i) * 64 + jc];
      #pragma unroll
      for (int u = 0; u < 4; ++u) {
        float4 n4 = *(const float4*)&norm_s[tb + u][c];
        a[u] += n4.x * w4[0] + n4.y * w4[1] + n4.z * w4[2] + n4.w * w4[3];
      }
    }
    #pragma unroll
    for (int u = 0; u < 4; ++u)
      h_s[tb + u][jc] = a[u] > 0.f ? a[u] : NSL * a[u];
  }
  __syncthreads();

  float bn[TB];
  {
    float b2j = b2[j];
    #pragma unroll
    for (int t = 0; t < TB; ++t) bn[t] = b2j + np[t];
    #pragma unroll 2
    for (int i = 0; i < 64; i += 4) {
      float w4[4];
      #pragma unroll
      for (int ii = 0; ii < 4; ++ii) w4[ii] = w2[(i + ii) * 128 + j];
      #pragma unroll
      for (int t = 0; t < TB; ++t) {
        float4 h4 = *(const float4*)&h_s[t][i];
        bn[t] += h4.x * w4[0] + h4.y * w4[1] + h4.z * w4[2] + h4.w * w4[3];
      }
    }
  }
  #pragma unroll
  for (int t = 0; t < TB; ++t) {
    float ratio = (zmask >> t) & 1 ? 1.f : bn[t] / np[t];
    float* od = out + (size_t)(t0 + t) * 384;
    od[j] = p0[t] * ratio; od[128 + j] = p1[t] * ratio; od[256 + j] = p2[t] * ratio;
  }
}

// ---------------------------------------------------------------------------
extern "C" void kernel_launch(void* const* d_in, const int* in_sizes, int n_in,
                              void* d_out, int out_size, void* d_ws, size_t ws_size,
                              hipStream_t stream) {
  const float* qfts   = (const float*)d_in[0];
  const float* kvfts  = (const float*)d_in[1];
  const float* w_q_in = (const float*)d_in[2];
  const float* q_w1   = (const float*)d_in[3];
  const float* q_b1   = (const float*)d_in[4];
  const float* q_w2   = (const float*)d_in[5];
  const float* q_b2   = (const float*)d_in[6];
  const float* w_kv_in= (const float*)d_in[7];
  const float* kv_w1  = (const float*)d_in[8];
  const float* kv_b1  = (const float*)d_in[9];
  const float* kv_w2  = (const float*)d_in[10];
  const float* kv_b2  = (const float*)d_in[11];
  const float* w_q    = (const float*)d_in[12];
  const float* w_k    = (const float*)d_in[13];
  const float* w_v    = (const float*)d_in[14];
  const float* w_out  = (const float*)d_in[15];
  const float* o_w1   = (const float*)d_in[16];
  const float* o_b1   = (const float*)d_in[17];
  const float* o_w2   = (const float*)d_in[18];
  const float* o_b2   = (const float*)d_in[19];

  unsigned short* QW = (unsigned short*)d_ws;
  unsigned short* KW = QW + 3145728;
  unsigned short* VW = KW + 3145728;
  float* Obuf = (float*)(VW + 3145728);

  dim3 pg(BB * NN / TB, 2);
  pre_kernel<<<pg, 128, 0, stream>>>(qfts, kvfts,
                                     w_q_in, q_w1, q_b1, q_w2, q_b2,
                                     w_kv_in, kv_w1, kv_b1, kv_w2, kv_b2,
                                     w_q, w_k, w_v, QW, KW, VW);
  dim3 ag(32, 16);
  attn_kernel<<<ag, 512, 0, stream>>>(QW, KW, VW, Obuf);
  out_kernel<<<BB * NN / TB, 128, 0, stream>>>(Obuf, w_out, o_w1, o_b1, o_w2, o_b2, (float*)d_out);
}

// Round 5
// 160.563 us; speedup vs baseline: 3.4581x; 1.1553x over previous
//
#include <hip/hip_runtime.h>
#include <math.h>

#define EPSV 1e-6f
#define NSL  0.2f
#define BB   2
#define NN   2048
#define HH   8
#define TB   4

typedef short bf16x8 __attribute__((ext_vector_type(8)));
typedef float f32x4  __attribute__((ext_vector_type(4)));

__device__ __forceinline__ unsigned short f2bf(float x) {
  union { float f; unsigned int u; } v; v.f = x;
  unsigned int r = v.u + 0x7FFF + ((v.u >> 16) & 1);
  return (unsigned short)(r >> 16);
}
__device__ __forceinline__ float bf2f(unsigned short h) {
  union { float f; unsigned int u; } v; v.u = ((unsigned int)h) << 16;
  return v.f;
}

// Workspace fragment layouts (bf16 hi/lo planes):
// QW/KW per (hb, tile16): [hl 2][768]: c0=[lane64][8] @0, c1=[lane<32][8] @512
// VW per (hb, kc32, f):   [hl 2][512]: [lane64][8]

// ---------------------------------------------------------------------------
// pre: merged q/kv branch (blockIdx.y: 0=q, 1=kv). 4 tokens / 128 threads.
// ---------------------------------------------------------------------------
__global__ __launch_bounds__(128) void pre_kernel(
    const float* __restrict__ qfts, const float* __restrict__ kvfts,
    const float* __restrict__ wq_in, const float* __restrict__ qw1, const float* __restrict__ qb1,
    const float* __restrict__ qw2, const float* __restrict__ qb2,
    const float* __restrict__ wkv_in, const float* __restrict__ kw1, const float* __restrict__ kb1,
    const float* __restrict__ kw2, const float* __restrict__ kb2,
    const float* __restrict__ w_q, const float* __restrict__ w_k, const float* __restrict__ w_v,
    unsigned short* __restrict__ QW, unsigned short* __restrict__ KW, unsigned short* __restrict__ VW)
{
  const bool is_kv = blockIdx.y != 0;
  const float* x_in = is_kv ? kvfts : qfts;
  const float* w_in = is_kv ? wkv_in : wq_in;
  const float* w1   = is_kv ? kw1 : qw1;
  const float* b1   = is_kv ? kb1 : qb1;
  const float* w2   = is_kv ? kw2 : qw2;
  const float* b2   = is_kv ? kb2 : qb2;
  const float* w_p  = is_kv ? w_k : w_q;
  unsigned short* FW = is_kv ? KW : QW;
  const float ln_sc = is_kv ? 1.f : 0.25f;   // fold 1/sqrt(hd) into Q

  const int t0 = blockIdx.x * TB;
  const int j = threadIdx.x;
  __shared__ float xs[TB][192];
  __shared__ float norm_s[TB][128];
  __shared__ float h_s[TB][64];
  __shared__ float f_s[TB][3][128];

  {
    const float4* src = (const float4*)(x_in + (size_t)t0 * 192);
    float4* dst = (float4*)&xs[0][0];
    dst[j] = src[j];
    if (j < 64) dst[128 + j] = src[128 + j];
  }
  __syncthreads();

  float p0[TB], p1[TB], p2[TB];
  #pragma unroll
  for (int t = 0; t < TB; ++t) { p0[t] = 0.f; p1[t] = 0.f; p2[t] = 0.f; }
  #pragma unroll 2
  for (int c = 0; c < 64; c += 4) {
    float w4[4];
    #pragma unroll
    for (int i = 0; i < 4; ++i) w4[i] = w_in[(c + i) * 128 + j];
    #pragma unroll
    for (int t = 0; t < TB; ++t) {
      float4 x0 = *(const float4*)&xs[t][c];
      float4 x1 = *(const float4*)&xs[t][64 + c];
      float4 x2 = *(const float4*)&xs[t][128 + c];
      p0[t] += x0.x * w4[0] + x0.y * w4[1] + x0.z * w4[2] + x0.w * w4[3];
      p1[t] += x1.x * w4[0] + x1.y * w4[1] + x1.z * w4[2] + x1.w * w4[3];
      p2[t] += x2.x * w4[0] + x2.y * w4[1] + x2.z * w4[2] + x2.w * w4[3];
    }
  }
  float np[TB]; int zmask = 0;
  #pragma unroll
  for (int t = 0; t < TB; ++t) {
    float nn = sqrtf(p0[t] * p0[t] + p1[t] * p1[t] + p2[t] * p2[t]);
    if (nn <= EPSV) zmask |= (1 << t);
    np[t] = nn + EPSV;
    norm_s[t][j] = np[t];
  }
  __syncthreads();

  {
    const int jc = j & 63;
    const int tb = (j >> 6) * 2;
    float a[2];
    float bb1 = b1[jc];
    #pragma unroll
    for (int u = 0; u < 2; ++u) a[u] = bb1;
    #pragma unroll 2
    for (int c = 0; c < 128; c += 4) {
      float w4[4];
      #pragma unroll
      for (int i = 0; i < 4; ++i) w4[i] = w1[(c + i) * 64 + jc];
      #pragma unroll
      for (int u = 0; u < 2; ++u) {
        float4 n4 = *(const float4*)&norm_s[tb + u][c];
        a[u] += n4.x * w4[0] + n4.y * w4[1] + n4.z * w4[2] + n4.w * w4[3];
      }
    }
    #pragma unroll
    for (int u = 0; u < 2; ++u)
      h_s[tb + u][jc] = a[u] > 0.f ? a[u] : NSL * a[u];
  }
  __syncthreads();

  float bn[TB];
  {
    float b2j = b2[j];
    #pragma unroll
    for (int t = 0; t < TB; ++t) bn[t] = b2j + np[t];
    #pragma unroll 2
    for (int i = 0; i < 64; i += 4) {
      float w4[4];
      #pragma unroll
      for (int ii = 0; ii < 4; ++ii) w4[ii] = w2[(i + ii) * 128 + j];
      #pragma unroll
      for (int t = 0; t < TB; ++t) {
        float4 h4 = *(const float4*)&h_s[t][i];
        bn[t] += h4.x * w4[0] + h4.y * w4[1] + h4.z * w4[2] + h4.w * w4[3];
      }
    }
  }
  #pragma unroll
  for (int t = 0; t < TB; ++t) {
    float ratio = (zmask >> t) & 1 ? 1.f : bn[t] / np[t];
    f_s[t][0][j] = p0[t] * ratio; f_s[t][1][j] = p1[t] * ratio; f_s[t][2][j] = p2[t] * ratio;
  }
  __syncthreads();

  const int hh = j >> 4, dd = j & 15;

  // main projection (+ EV layernorm) -> FW (QW or KW)
  {
    float q0[TB], q1[TB], q2[TB];
    #pragma unroll
    for (int t = 0; t < TB; ++t) { q0[t] = 0.f; q1[t] = 0.f; q2[t] = 0.f; }
    #pragma unroll 2
    for (int c = 0; c < 128; c += 4) {
      float w4[4];
      #pragma unroll
      for (int i = 0; i < 4; ++i) w4[i] = w_p[(c + i) * 128 + j];
      #pragma unroll
      for (int t = 0; t < TB; ++t) {
        float4 f0 = *(const float4*)&f_s[t][0][c];
        float4 f1 = *(const float4*)&f_s[t][1][c];
        float4 f2 = *(const float4*)&f_s[t][2][c];
        q0[t] += f0.x * w4[0] + f0.y * w4[1] + f0.z * w4[2] + f0.w * w4[3];
        q1[t] += f1.x * w4[0] + f1.y * w4[1] + f1.z * w4[2] + f1.w * w4[3];
        q2[t] += f2.x * w4[0] + f2.y * w4[1] + f2.z * w4[2] + f2.w * w4[3];
      }
    }
    #pragma unroll
    for (int t = 0; t < TB; ++t) {
      float ss = q0[t] * q0[t] + q1[t] * q1[t] + q2[t] * q2[t];
      ss += __shfl_xor(ss, 1, 16);
      ss += __shfl_xor(ss, 2, 16);
      ss += __shfl_xor(ss, 4, 16);
      ss += __shfl_xor(ss, 8, 16);
      float inv = ln_sc / (sqrtf(ss * (1.f / 16.f)) + EPSV);
      const int tok = t0 + t;
      const int b = tok >> 11, n = tok & (NN - 1);
      const int hb = hh * BB + b;
      const size_t base = (size_t)(hb * 128 + (n >> 4)) * 1536;
      const int row = n & 15;
      float vals[3] = {q0[t] * inv, q1[t] * inv, q2[t] * inv};
      #pragma unroll
      for (int f = 0; f < 3; ++f) {
        int d = f * 16 + dd;
        int off;
        if (d < 32) off = ((d >> 3) * 16 + row) * 8 + (d & 7);
        else        off = 512 + (((d - 32) >> 3) * 16 + row) * 8 + ((d - 32) & 7);
        unsigned short hi = f2bf(vals[f]);
        FW[base + off] = hi;
        FW[base + 768 + off] = f2bf(vals[f] - bf2f(hi));
      }
    }
  }
  // V projection (kv branch only) -> VW
  if (is_kv) {
    float v0[TB], v1[TB], v2[TB];
    #pragma unroll
    for (int t = 0; t < TB; ++t) { v0[t] = 0.f; v1[t] = 0.f; v2[t] = 0.f; }
    #pragma unroll 2
    for (int c = 0; c < 128; c += 4) {
      float w4[4];
      #pragma unroll
      for (int i = 0; i < 4; ++i) w4[i] = w_v[(c + i) * 128 + j];
      #pragma unroll
      for (int t = 0; t < TB; ++t) {
        float4 f0 = *(const float4*)&f_s[t][0][c];
        float4 f1 = *(const float4*)&f_s[t][1][c];
        float4 f2 = *(const float4*)&f_s[t][2][c];
        v0[t] += f0.x * w4[0] + f0.y * w4[1] + f0.z * w4[2] + f0.w * w4[3];
        v1[t] += f1.x * w4[0] + f1.y * w4[1] + f1.z * w4[2] + f1.w * w4[3];
        v2[t] += f2.x * w4[0] + f2.y * w4[1] + f2.z * w4[2] + f2.w * w4[3];
      }
    }
    #pragma unroll
    for (int t = 0; t < TB; ++t) {
      const int tok = t0 + t;
      const int b = tok >> 11, n = tok & (NN - 1);
      const int hb = hh * BB + b;
      const int off = (((n & 31) >> 3) * 16 + dd) * 8 + (n & 7);
      float vals[3] = {v0[t], v1[t], v2[t]};
      #pragma unroll
      for (int f = 0; f < 3; ++f) {
        const size_t vbase = (size_t)((hb * 64 + (n >> 5)) * 3 + f) * 1024;
        unsigned short hi = f2bf(vals[f]);
        VW[vbase + off] = hi;
        VW[vbase + 512 + off] = f2bf(vals[f] - bf2f(hi));
      }
    }
  }
}

// ---------------------------------------------------------------------------
// attention: MFMA flash, 4-way K-split.
// 512 threads = 8 waves: qt = w&1 (q-tile of 16), kq = w>>1 (512-key quarter).
// Per-wave online softmax; quarters merged through LDS (reusing plds space).
// ---------------------------------------------------------------------------
__global__ __launch_bounds__(512) void attn_kernel(
    const unsigned short* __restrict__ QW, const unsigned short* __restrict__ KW,
    const unsigned short* __restrict__ VW, float* __restrict__ Ob)
{
  const int lane = threadIdx.x & 63;
  const int w = threadIdx.x >> 6;
  const int qt = w & 1;
  const int kq = w >> 1;               // 0..3
  const int hb = blockIdx.y;
  const int t = blockIdx.x * 2 + qt;
  const int q = lane & 15, g = lane >> 4;

  __shared__ __align__(16) char smem[8 * 2 * 1152 * 2];   // 36864 B
  unsigned short (*plds)[2][1152] = (unsigned short (*)[2][1152])smem;
  float* comb = (float*)smem;          // reused at merge: [qt][kq-1][lane][14]

  const size_t qbase = (size_t)(hb * 128 + t) * 1536;
  bf16x8 qh0 = *(const bf16x8*)(QW + qbase + lane * 8);
  bf16x8 ql0 = *(const bf16x8*)(QW + qbase + 768 + lane * 8);
  bf16x8 qh1 = {0, 0, 0, 0, 0, 0, 0, 0};
  bf16x8 ql1 = {0, 0, 0, 0, 0, 0, 0, 0};
  if (lane < 32) {
    qh1 = *(const bf16x8*)(QW + qbase + 512 + lane * 8);
    ql1 = *(const bf16x8*)(QW + qbase + 768 + 512 + lane * 8);
  }

  f32x4 o[3];
  #pragma unroll
  for (int f = 0; f < 3; ++f) o[f] = (f32x4){0.f, 0.f, 0.f, 0.f};
  float m = -INFINITY, lsum = 0.f;

  for (int T = kq * 8; T < kq * 8 + 8; ++T) {
    f32x4 sc[4];
    __builtin_amdgcn_s_setprio(1);
    #pragma unroll
    for (int st = 0; st < 4; ++st) {
      const size_t kb = (size_t)(hb * 128 + T * 4 + st) * 1536;
      bf16x8 kh0 = *(const bf16x8*)(KW + kb + lane * 8);
      bf16x8 kl0 = *(const bf16x8*)(KW + kb + 768 + lane * 8);
      bf16x8 kh1 = *(const bf16x8*)(KW + kb + 512 + lane * 8);
      bf16x8 kl1 = *(const bf16x8*)(KW + kb + 768 + 512 + lane * 8);
      f32x4 a = {0.f, 0.f, 0.f, 0.f};
      a = __builtin_amdgcn_mfma_f32_16x16x32_bf16(kh0, qh0, a, 0, 0, 0);
      a = __builtin_amdgcn_mfma_f32_16x16x32_bf16(kh0, ql0, a, 0, 0, 0);
      a = __builtin_amdgcn_mfma_f32_16x16x32_bf16(kl0, qh0, a, 0, 0, 0);
      a = __builtin_amdgcn_mfma_f32_16x16x32_bf16(kh1, qh1, a, 0, 0, 0);
      a = __builtin_amdgcn_mfma_f32_16x16x32_bf16(kh1, ql1, a, 0, 0, 0);
      a = __builtin_amdgcn_mfma_f32_16x16x32_bf16(kl1, qh1, a, 0, 0, 0);
      sc[st] = a;
    }
    __builtin_amdgcn_s_setprio(0);

    float tm = sc[0][0];
    #pragma unroll
    for (int st = 0; st < 4; ++st)
      #pragma unroll
      for (int r = 0; r < 4; ++r) tm = fmaxf(tm, sc[st][r]);
    tm = fmaxf(tm, __shfl_xor(tm, 16));
    tm = fmaxf(tm, __shfl_xor(tm, 32));
    float mnew = fmaxf(m, tm);
    float scale = __expf(m - mnew);
    lsum *= scale;
    #pragma unroll
    for (int f = 0; f < 3; ++f) {
      o[f][0] *= scale; o[f][1] *= scale; o[f][2] *= scale; o[f][3] *= scale;
    }
    float lp = 0.f;
    #pragma unroll
    for (int st = 0; st < 4; ++st) {
      float p0 = __expf(sc[st][0] - mnew);
      float p1 = __expf(sc[st][1] - mnew);
      float p2 = __expf(sc[st][2] - mnew);
      float p3 = __expf(sc[st][3] - mnew);
      lp += (p0 + p1) + (p2 + p3);
      unsigned short h0 = f2bf(p0), h1 = f2bf(p1), h2 = f2bf(p2), h3 = f2bf(p3);
      uint2 uh = {(unsigned)h0 | ((unsigned)h1 << 16), (unsigned)h2 | ((unsigned)h3 << 16)};
      unsigned short l0 = f2bf(p0 - bf2f(h0)), l1 = f2bf(p1 - bf2f(h1));
      unsigned short l2 = f2bf(p2 - bf2f(h2)), l3 = f2bf(p3 - bf2f(h3));
      uint2 ul = {(unsigned)l0 | ((unsigned)l1 << 16), (unsigned)l2 | ((unsigned)l3 << 16)};
      *(uint2*)&plds[w][0][q * 72 + st * 16 + g * 4] = uh;
      *(uint2*)&plds[w][1][q * 72 + st * 16 + g * 4] = ul;
    }
    lp += __shfl_xor(lp, 16);
    lp += __shfl_xor(lp, 32);
    lsum += lp;
    m = mnew;

    asm volatile("s_waitcnt lgkmcnt(0)" ::: "memory");

    __builtin_amdgcn_s_setprio(1);
    #pragma unroll
    for (int c = 0; c < 2; ++c) {
      const int kc = T * 2 + c;
      bf16x8 pbh = *(const bf16x8*)&plds[w][0][q * 72 + c * 32 + g * 8];
      bf16x8 pbl = *(const bf16x8*)&plds[w][1][q * 72 + c * 32 + g * 8];
      #pragma unroll
      for (int f = 0; f < 3; ++f) {
        const size_t vb = (size_t)((hb * 64 + kc) * 3 + f) * 1024;
        bf16x8 vh = *(const bf16x8*)(VW + vb + lane * 8);
        bf16x8 vl = *(const bf16x8*)(VW + vb + 512 + lane * 8);
        o[f] = __builtin_amdgcn_mfma_f32_16x16x32_bf16(vh, pbh, o[f], 0, 0, 0);
        o[f] = __builtin_amdgcn_mfma_f32_16x16x32_bf16(vh, pbl, o[f], 0, 0, 0);
        o[f] = __builtin_amdgcn_mfma_f32_16x16x32_bf16(vl, pbh, o[f], 0, 0, 0);
      }
    }
    __builtin_amdgcn_s_setprio(0);
  }

  // ---- merge the 4 key-quarters (plds space reused as comb) ----
  __syncthreads();   // all waves done with plds
  if (kq != 0) {
    float* cb = comb + ((size_t)(qt * 3 + (kq - 1)) * 64 + lane) * 14;
    #pragma unroll
    for (int f = 0; f < 3; ++f)
      #pragma unroll
      for (int r = 0; r < 4; ++r) cb[f * 4 + r] = o[f][r];
    cb[12] = m; cb[13] = lsum;
  }
  __syncthreads();
  if (kq == 0) {
    #pragma unroll
    for (int i = 0; i < 3; ++i) {
      const float* cb = comb + ((size_t)(qt * 3 + i) * 64 + lane) * 14;
      float m1 = cb[12], l1 = cb[13];
      float mn = fmaxf(m, m1);
      float s0 = __expf(m - mn), s1 = __expf(m1 - mn);
      lsum = lsum * s0 + l1 * s1;
      #pragma unroll
      for (int f = 0; f < 3; ++f)
        #pragma unroll
        for (int r = 0; r < 4; ++r)
          o[f][r] = o[f][r] * s0 + cb[f * 4 + r] * s1;
      m = mn;
    }
    float invl = 1.f / lsum;
    const int h_ = hb >> 1, b_ = hb & 1;
    const int n = t * 16 + q;
    #pragma unroll
    for (int f = 0; f < 3; ++f) {
      float4 st4 = {o[f][0] * invl, o[f][1] * invl, o[f][2] * invl, o[f][3] * invl};
      *(float4*)&Ob[(((size_t)(b_ * NN + n)) * 3 + f) * 128 + h_ * 16 + g * 4] = st4;
    }
  }
}

// ---------------------------------------------------------------------------
// out: out = ev_nonlin(resi @ w_out). 4 tokens / 128 threads.
// ---------------------------------------------------------------------------
__global__ __launch_bounds__(128) void out_kernel(
    const float* __restrict__ Ob, const float* __restrict__ w_out,
    const float* __restrict__ w1, const float* __restrict__ b1,
    const float* __restrict__ w2, const float* __restrict__ b2,
    float* __restrict__ out)
{
  const int t0 = blockIdx.x * TB;
  const int j = threadIdx.x;
  __shared__ float rs[TB][384];
  __shared__ float norm_s[TB][128];
  __shared__ float h_s[TB][64];

  {
    const float4* src = (const float4*)(Ob + (size_t)t0 * 384);
    float4* dst = (float4*)&rs[0][0];
    #pragma unroll
    for (int i = 0; i < 3; ++i) dst[j + i * 128] = src[j + i * 128];
  }
  __syncthreads();

  float p0[TB], p1[TB], p2[TB];
  #pragma unroll
  for (int t = 0; t < TB; ++t) { p0[t] = 0.f; p1[t] = 0.f; p2[t] = 0.f; }
  #pragma unroll 2
  for (int c = 0; c < 128; c += 4) {
    float w4[4];
    #pragma unroll
    for (int i = 0; i < 4; ++i) w4[i] = w_out[(c + i) * 128 + j];
    #pragma unroll
    for (int t = 0; t < TB; ++t) {
      float4 x0 = *(const float4*)&rs[t][c];
      float4 x1 = *(const float4*)&rs[t][128 + c];
      float4 x2 = *(const float4*)&rs[t][256 + c];
      p0[t] += x0.x * w4[0] + x0.y * w4[1] + x0.z * w4[2] + x0.w * w4[3];
      p1[t] += x1.x * w4[0] + x1.y * w4[1] + x1.z * w4[2] + x1.w * w4[3];
      p2[t] += x2.x * w4[0] + x2.y * w4[1] + x2.z * w4[2] + x2.w * w4[3];
    }
  }
  float np[TB]; int zmask = 0;
  #pragma unroll
  for (int t = 0; t < TB; ++t) {
    float nn = sqrtf(p0[t] * p0[t] + p1[t] * p1[t] + p2[t] * p2[t]);
    if (nn <= EPSV) zmask |= (1 << t);
    np[t] = nn + EPSV;
    norm_s[t][j] = np[t];
  }
  __syncthreads();

  {
    const int jc = j & 63;
    const int tb = (j >> 6) * 2;
    float a[2];
    float bb1 = b1[jc];
    #pragma unroll
    for (int u = 0; u < 2; ++u) a[u] = bb1;
    #pragma unroll 2
    for (int c = 0; c < 128; c += 4) {
      float w4[4];
      #pragma unroll
      for (int i = 0; i < 4; ++i) w4[i] = w1[(c + i) * 64 + jc];
      #pragma unroll
      for (int u = 0; u < 2; ++u) {
        float4 n4 = *(const float4*)&norm_s[tb + u][c];
        a[u] += n4.x * w4[0] + n4.y * w4[1] + n4.z * w4[2] + n4.w * w4[3];
      }
    }
    #pragma unroll
    for (int u = 0; u < 2; ++u)
      h_s[tb + u][jc] = a[u] > 0.f ? a[u] : NSL * a[u];
  }
  __syncthreads();

  float bn[TB];
  {
    float b2j = b2[j];
    #pragma unroll
    for (int t = 0; t < TB; ++t) bn[t] = b2j + np[t];
    #pragma unroll 2
    for (int i = 0; i < 64; i += 4) {
      float w4[4];
      #pragma unroll
      for (int ii = 0; ii < 4; ++ii) w4[ii] = w2[(i + ii) * 128 + j];
      #pragma unroll
      for (int t = 0; t < TB; ++t) {
        float4 h4 = *(const float4*)&h_s[t][i];
        bn[t] += h4.x * w4[0] + h4.y * w4[1] + h4.z * w4[2] + h4.w * w4[3];
      }
    }
  }
  #pragma unroll
  for (int t = 0; t < TB; ++t) {
    float ratio = (zmask >> t) & 1 ? 1.f : bn[t] / np[t];
    float* od = out + (size_t)(t0 + t) * 384;
    od[j] = p0[t] * ratio; od[128 + j] = p1[t] * ratio; od[256 + j] = p2[t] * ratio;
  }
}

// ---------------------------------------------------------------------------
extern "C" void kernel_launch(void* const* d_in, const int* in_sizes, int n_in,
                              void* d_out, int out_size, void* d_ws, size_t ws_size,
                              hipStream_t stream) {
  const float* qfts   = (const float*)d_in[0];
  const float* kvfts  = (const float*)d_in[1];
  const float* w_q_in = (const float*)d_in[2];
  const float* q_w1   = (const float*)d_in[3];
  const float* q_b1   = (const float*)d_in[4];
  const float* q_w2   = (const float*)d_in[5];
  const float* q_b2   = (const float*)d_in[6];
  const float* w_kv_in= (const float*)d_in[7];
  const float* kv_w1  = (const float*)d_in[8];
  const float* kv_b1  = (const float*)d_in[9];
  const float* kv_w2  = (const float*)d_in[10];
  const float* kv_b2  = (const float*)d_in[11];
  const float* w_q    = (const float*)d_in[12];
  const float* w_k    = (const float*)d_in[13];
  const float* w_v    = (const float*)d_in[14];
  const float* w_out  = (const float*)d_in[15];
  const float* o_w1   = (const float*)d_in[16];
  const float* o_b1   = (const float*)d_in[17];
  const float* o_w2   = (const float*)d_in[18];
  const float* o_b2   = (const float*)d_in[19];

  unsigned short* QW = (unsigned short*)d_ws;
  unsigned short* KW = QW + 3145728;
  unsigned short* VW = KW + 3145728;
  float* Obuf = (float*)(VW + 3145728);

  dim3 pg(BB * NN / TB, 2);
  pre_kernel<<<pg, 128, 0, stream>>>(qfts, kvfts,
                                     w_q_in, q_w1, q_b1, q_w2, q_b2,
                                     w_kv_in, kv_w1, kv_b1, kv_w2, kv_b2,
                                     w_q, w_k, w_v, QW, KW, VW);
  dim3 ag(64, 16);
  attn_kernel<<<ag, 512, 0, stream>>>(QW, KW, VW, Obuf);
  out_kernel<<<BB * NN / TB, 128, 0, stream>>>(Obuf, w_out, o_w1, o_b1, o_w2, o_b2, (float*)d_out);
}

// Round 7
// 124.230 us; speedup vs baseline: 4.4695x; 1.2925x over previous
//
#include <hip/hip_runtime.h>
#include <math.h>

#define EPSV 1e-6f
#define NSL  0.2f
#define BB   2
#define NN   2048
#define HH   8
#define TB   4

typedef short bf16x8 __attribute__((ext_vector_type(8)));
typedef float f32x4  __attribute__((ext_vector_type(4)));

__device__ __forceinline__ unsigned short f2bf(float x) {
  union { float f; unsigned int u; } v; v.f = x;
  unsigned int r = v.u + 0x7FFF + ((v.u >> 16) & 1);
  return (unsigned short)(r >> 16);
}
__device__ __forceinline__ float bf2f(unsigned short h) {
  union { float f; unsigned int u; } v; v.u = ((unsigned int)h) << 16;
  return v.f;
}
__device__ __forceinline__ unsigned cvt_pk_bf16(float a, float b) {
  unsigned r;
  asm("v_cvt_pk_bf16_f32 %0, %1, %2" : "=v"(r) : "v"(a), "v"(b));
  return r;   // lo16 = bf16(a), hi16 = bf16(b), RNE
}

// Workspace fragment layouts (bf16 hi/lo planes):
// QW/KW per (hb, tile16): [hl 2][768]: c0=[lane64][8] @0, c1=[lane<32][8] @512
// VW per (hb, kc32, f):   [hl 2][512]: [lane64][8]

// ---------------------------------------------------------------------------
// pre: merged q/kv branch (blockIdx.y: 0=q, 1=kv). 4 tokens / 128 threads.
// Q is scaled by 0.25*log2(e): attention softmax runs in exp2 domain.
// ---------------------------------------------------------------------------
__global__ __launch_bounds__(128) void pre_kernel(
    const float* __restrict__ qfts, const float* __restrict__ kvfts,
    const float* __restrict__ wq_in, const float* __restrict__ qw1, const float* __restrict__ qb1,
    const float* __restrict__ qw2, const float* __restrict__ qb2,
    const float* __restrict__ wkv_in, const float* __restrict__ kw1, const float* __restrict__ kb1,
    const float* __restrict__ kw2, const float* __restrict__ kb2,
    const float* __restrict__ w_q, const float* __restrict__ w_k, const float* __restrict__ w_v,
    unsigned short* __restrict__ QW, unsigned short* __restrict__ KW, unsigned short* __restrict__ VW)
{
  const bool is_kv = blockIdx.y != 0;
  const float* x_in = is_kv ? kvfts : qfts;
  const float* w_in = is_kv ? wkv_in : wq_in;
  const float* w1   = is_kv ? kw1 : qw1;
  const float* b1   = is_kv ? kb1 : qb1;
  const float* w2   = is_kv ? kw2 : qw2;
  const float* b2   = is_kv ? kb2 : qb2;
  const float* w_p  = is_kv ? w_k : w_q;
  unsigned short* FW = is_kv ? KW : QW;
  const float ln_sc = is_kv ? 1.f : 0.25f * 1.44269504088896f;

  const int t0 = blockIdx.x * TB;
  const int j = threadIdx.x;
  __shared__ float xs[TB][192];
  __shared__ float norm_s[TB][128];
  __shared__ float h_s[TB][64];
  __shared__ float f_s[TB][3][128];

  {
    const float4* src = (const float4*)(x_in + (size_t)t0 * 192);
    float4* dst = (float4*)&xs[0][0];
    dst[j] = src[j];
    if (j < 64) dst[128 + j] = src[128 + j];
  }
  __syncthreads();

  float p0[TB], p1[TB], p2[TB];
  #pragma unroll
  for (int t = 0; t < TB; ++t) { p0[t] = 0.f; p1[t] = 0.f; p2[t] = 0.f; }
  #pragma unroll 2
  for (int c = 0; c < 64; c += 4) {
    float w4[4];
    #pragma unroll
    for (int i = 0; i < 4; ++i) w4[i] = w_in[(c + i) * 128 + j];
    #pragma unroll
    for (int t = 0; t < TB; ++t) {
      float4 x0 = *(const float4*)&xs[t][c];
      float4 x1 = *(const float4*)&xs[t][64 + c];
      float4 x2 = *(const float4*)&xs[t][128 + c];
      p0[t] += x0.x * w4[0] + x0.y * w4[1] + x0.z * w4[2] + x0.w * w4[3];
      p1[t] += x1.x * w4[0] + x1.y * w4[1] + x1.z * w4[2] + x1.w * w4[3];
      p2[t] += x2.x * w4[0] + x2.y * w4[1] + x2.z * w4[2] + x2.w * w4[3];
    }
  }
  float np[TB]; int zmask = 0;
  #pragma unroll
  for (int t = 0; t < TB; ++t) {
    float nn = sqrtf(p0[t] * p0[t] + p1[t] * p1[t] + p2[t] * p2[t]);
    if (nn <= EPSV) zmask |= (1 << t);
    np[t] = nn + EPSV;
    norm_s[t][j] = np[t];
  }
  __syncthreads();

  {
    const int jc = j & 63;
    const int tb = (j >> 6) * 2;
    float a[2];
    float bb1 = b1[jc];
    #pragma unroll
    for (int u = 0; u < 2; ++u) a[u] = bb1;
    #pragma unroll 2
    for (int c = 0; c < 128; c += 4) {
      float w4[4];
      #pragma unroll
      for (int i = 0; i < 4; ++i) w4[i] = w1[(c + i) * 64 + jc];
      #pragma unroll
      for (int u = 0; u < 2; ++u) {
        float4 n4 = *(const float4*)&norm_s[tb + u][c];
        a[u] += n4.x * w4[0] + n4.y * w4[1] + n4.z * w4[2] + n4.w * w4[3];
      }
    }
    #pragma unroll
    for (int u = 0; u < 2; ++u)
      h_s[tb + u][jc] = a[u] > 0.f ? a[u] : NSL * a[u];
  }
  __syncthreads();

  float bn[TB];
  {
    float b2j = b2[j];
    #pragma unroll
    for (int t = 0; t < TB; ++t) bn[t] = b2j + np[t];
    #pragma unroll 2
    for (int i = 0; i < 64; i += 4) {
      float w4[4];
      #pragma unroll
      for (int ii = 0; ii < 4; ++ii) w4[ii] = w2[(i + ii) * 128 + j];
      #pragma unroll
      for (int t = 0; t < TB; ++t) {
        float4 h4 = *(const float4*)&h_s[t][i];
        bn[t] += h4.x * w4[0] + h4.y * w4[1] + h4.z * w4[2] + h4.w * w4[3];
      }
    }
  }
  #pragma unroll
  for (int t = 0; t < TB; ++t) {
    float ratio = (zmask >> t) & 1 ? 1.f : bn[t] / np[t];
    f_s[t][0][j] = p0[t] * ratio; f_s[t][1][j] = p1[t] * ratio; f_s[t][2][j] = p2[t] * ratio;
  }
  __syncthreads();

  const int hh = j >> 4, dd = j & 15;

  // main projection (+ EV layernorm) -> FW (QW or KW)
  {
    float q0[TB], q1[TB], q2[TB];
    #pragma unroll
    for (int t = 0; t < TB; ++t) { q0[t] = 0.f; q1[t] = 0.f; q2[t] = 0.f; }
    #pragma unroll 2
    for (int c = 0; c < 128; c += 4) {
      float w4[4];
      #pragma unroll
      for (int i = 0; i < 4; ++i) w4[i] = w_p[(c + i) * 128 + j];
      #pragma unroll
      for (int t = 0; t < TB; ++t) {
        float4 f0 = *(const float4*)&f_s[t][0][c];
        float4 f1 = *(const float4*)&f_s[t][1][c];
        float4 f2 = *(const float4*)&f_s[t][2][c];
        q0[t] += f0.x * w4[0] + f0.y * w4[1] + f0.z * w4[2] + f0.w * w4[3];
        q1[t] += f1.x * w4[0] + f1.y * w4[1] + f1.z * w4[2] + f1.w * w4[3];
        q2[t] += f2.x * w4[0] + f2.y * w4[1] + f2.z * w4[2] + f2.w * w4[3];
      }
    }
    #pragma unroll
    for (int t = 0; t < TB; ++t) {
      float ss = q0[t] * q0[t] + q1[t] * q1[t] + q2[t] * q2[t];
      ss += __shfl_xor(ss, 1, 16);
      ss += __shfl_xor(ss, 2, 16);
      ss += __shfl_xor(ss, 4, 16);
      ss += __shfl_xor(ss, 8, 16);
      float inv = ln_sc / (sqrtf(ss * (1.f / 16.f)) + EPSV);
      const int tok = t0 + t;
      const int b = tok >> 11, n = tok & (NN - 1);
      const int hb = hh * BB + b;
      const size_t base = (size_t)(hb * 128 + (n >> 4)) * 1536;
      const int row = n & 15;
      float vals[3] = {q0[t] * inv, q1[t] * inv, q2[t] * inv};
      #pragma unroll
      for (int f = 0; f < 3; ++f) {
        int d = f * 16 + dd;
        int off;
        if (d < 32) off = ((d >> 3) * 16 + row) * 8 + (d & 7);
        else        off = 512 + (((d - 32) >> 3) * 16 + row) * 8 + ((d - 32) & 7);
        unsigned short hi = f2bf(vals[f]);
        FW[base + off] = hi;
        FW[base + 768 + off] = f2bf(vals[f] - bf2f(hi));
      }
    }
  }
  // V projection (kv branch only) -> VW
  if (is_kv) {
    float v0[TB], v1[TB], v2[TB];
    #pragma unroll
    for (int t = 0; t < TB; ++t) { v0[t] = 0.f; v1[t] = 0.f; v2[t] = 0.f; }
    #pragma unroll 2
    for (int c = 0; c < 128; c += 4) {
      float w4[4];
      #pragma unroll
      for (int i = 0; i < 4; ++i) w4[i] = w_v[(c + i) * 128 + j];
      #pragma unroll
      for (int t = 0; t < TB; ++t) {
        float4 f0 = *(const float4*)&f_s[t][0][c];
        float4 f1 = *(const float4*)&f_s[t][1][c];
        float4 f2 = *(const float4*)&f_s[t][2][c];
        v0[t] += f0.x * w4[0] + f0.y * w4[1] + f0.z * w4[2] + f0.w * w4[3];
        v1[t] += f1.x * w4[0] + f1.y * w4[1] + f1.z * w4[2] + f1.w * w4[3];
        v2[t] += f2.x * w4[0] + f2.y * w4[1] + f2.z * w4[2] + f2.w * w4[3];
      }
    }
    #pragma unroll
    for (int t = 0; t < TB; ++t) {
      const int tok = t0 + t;
      const int b = tok >> 11, n = tok & (NN - 1);
      const int hb = hh * BB + b;
      const int off = (((n & 31) >> 3) * 16 + dd) * 8 + (n & 7);
      float vals[3] = {v0[t], v1[t], v2[t]};
      #pragma unroll
      for (int f = 0; f < 3; ++f) {
        const size_t vbase = (size_t)((hb * 64 + (n >> 5)) * 3 + f) * 1024;
        unsigned short hi = f2bf(vals[f]);
        VW[vbase + off] = hi;
        VW[vbase + 512 + off] = f2bf(vals[f] - bf2f(hi));
      }
    }
  }
}

// ---------------------------------------------------------------------------
// attention: MFMA flash, 4-way K-split, 32 q per wave (2 fragment sets
// sharing every K/V load). exp2-domain softmax with defer-max (THR=10),
// P stored hi-only bf16 via v_cvt_pk_bf16_f32.
// 512 threads = 8 waves: qt = w&1 (which 32-q half), kq = w>>1 (512-key quarter).
// ---------------------------------------------------------------------------
#define THR 10.0f

__global__ __launch_bounds__(512, 4) void attn_kernel(
    const unsigned short* __restrict__ QW, const unsigned short* __restrict__ KW,
    const unsigned short* __restrict__ VW, float* __restrict__ Ob)
{
  const int lane = threadIdx.x & 63;
  const int w = threadIdx.x >> 6;
  const int qt = w & 1;
  const int kq = w >> 1;               // 0..3
  const int hb = blockIdx.y;
  const int tA = blockIdx.x * 4 + qt * 2;   // two 16-q tiles: tA, tA+1
  const int q = lane & 15, g = lane >> 4;

  __shared__ unsigned short plds[8][2][1152];   // [wave][qset][16 q][72], hi bf16
  float* comb = (float*)plds;                    // merge overlay (28.7 KB)

  // Q fragments for both qsets
  bf16x8 qh0[2], ql0[2], qh1[2], ql1[2];
  #pragma unroll
  for (int qs = 0; qs < 2; ++qs) {
    const size_t qbase = (size_t)(hb * 128 + tA + qs) * 1536;
    qh0[qs] = *(const bf16x8*)(QW + qbase + lane * 8);
    ql0[qs] = *(const bf16x8*)(QW + qbase + 768 + lane * 8);
    qh1[qs] = (bf16x8){0,0,0,0,0,0,0,0};
    ql1[qs] = (bf16x8){0,0,0,0,0,0,0,0};
    if (lane < 32) {
      qh1[qs] = *(const bf16x8*)(QW + qbase + 512 + lane * 8);
      ql1[qs] = *(const bf16x8*)(QW + qbase + 768 + 512 + lane * 8);
    }
  }

  f32x4 o[2][3];
  #pragma unroll
  for (int qs = 0; qs < 2; ++qs)
    #pragma unroll
    for (int f = 0; f < 3; ++f) o[qs][f] = (f32x4){0.f, 0.f, 0.f, 0.f};
  float m[2] = {-INFINITY, -INFINITY}, l[2] = {0.f, 0.f};

  for (int T = kq * 8; T < kq * 8 + 8; ++T) {
    // ---- scores: 4 subtiles of 16 k, K fragments shared by both qsets ----
    f32x4 sc[2][4];
    __builtin_amdgcn_s_setprio(1);
    #pragma unroll
    for (int st = 0; st < 4; ++st) {
      const size_t kb = (size_t)(hb * 128 + T * 4 + st) * 1536;
      bf16x8 kh0 = *(const bf16x8*)(KW + kb + lane * 8);
      bf16x8 kl0 = *(const bf16x8*)(KW + kb + 768 + lane * 8);
      bf16x8 kh1 = *(const bf16x8*)(KW + kb + 512 + lane * 8);
      bf16x8 kl1 = *(const bf16x8*)(KW + kb + 768 + 512 + lane * 8);
      #pragma unroll
      for (int qs = 0; qs < 2; ++qs) {
        f32x4 a = {0.f, 0.f, 0.f, 0.f};
        a = __builtin_amdgcn_mfma_f32_16x16x32_bf16(kh0, qh0[qs], a, 0, 0, 0);
        a = __builtin_amdgcn_mfma_f32_16x16x32_bf16(kh0, ql0[qs], a, 0, 0, 0);
        a = __builtin_amdgcn_mfma_f32_16x16x32_bf16(kl0, qh0[qs], a, 0, 0, 0);
        a = __builtin_amdgcn_mfma_f32_16x16x32_bf16(kh1, qh1[qs], a, 0, 0, 0);
        a = __builtin_amdgcn_mfma_f32_16x16x32_bf16(kh1, ql1[qs], a, 0, 0, 0);
        a = __builtin_amdgcn_mfma_f32_16x16x32_bf16(kl1, qh1[qs], a, 0, 0, 0);
        sc[qs][st] = a;
      }
    }
    __builtin_amdgcn_s_setprio(0);

    // ---- online softmax (exp2 domain, defer-max) ----
    #pragma unroll
    for (int qs = 0; qs < 2; ++qs) {
      float tm = sc[qs][0][0];
      #pragma unroll
      for (int st = 0; st < 4; ++st)
        #pragma unroll
        for (int r = 0; r < 4; ++r) tm = fmaxf(tm, sc[qs][st][r]);
      tm = fmaxf(tm, __shfl_xor(tm, 16));
      tm = fmaxf(tm, __shfl_xor(tm, 32));
      if (__any(tm > m[qs] + THR)) {
        float mnew = fmaxf(m[qs], tm);
        float scl = __builtin_amdgcn_exp2f(m[qs] - mnew);
        l[qs] *= scl;
        #pragma unroll
        for (int f = 0; f < 3; ++f) {
          o[qs][f][0] *= scl; o[qs][f][1] *= scl;
          o[qs][f][2] *= scl; o[qs][f][3] *= scl;
        }
        m[qs] = mnew;
      }
      float lp = 0.f;
      #pragma unroll
      for (int st = 0; st < 4; ++st) {
        float p0 = __builtin_amdgcn_exp2f(sc[qs][st][0] - m[qs]);
        float p1 = __builtin_amdgcn_exp2f(sc[qs][st][1] - m[qs]);
        float p2 = __builtin_amdgcn_exp2f(sc[qs][st][2] - m[qs]);
        float p3 = __builtin_amdgcn_exp2f(sc[qs][st][3] - m[qs]);
        lp += (p0 + p1) + (p2 + p3);
        uint2 uh = {cvt_pk_bf16(p0, p1), cvt_pk_bf16(p2, p3)};
        *(uint2*)&plds[w][qs][q * 72 + st * 16 + g * 4] = uh;
      }
      lp += __shfl_xor(lp, 16);
      lp += __shfl_xor(lp, 32);
      l[qs] += lp;
    }

    asm volatile("s_waitcnt lgkmcnt(0)" ::: "memory");

    // ---- PV: O^T += V^T · P, V fragments shared by both qsets ----
    __builtin_amdgcn_s_setprio(1);
    #pragma unroll
    for (int c = 0; c < 2; ++c) {
      const int kc = T * 2 + c;
      bf16x8 pb[2];
      #pragma unroll
      for (int qs = 0; qs < 2; ++qs)
        pb[qs] = *(const bf16x8*)&plds[w][qs][q * 72 + c * 32 + g * 8];
      #pragma unroll
      for (int f = 0; f < 3; ++f) {
        const size_t vb = (size_t)((hb * 64 + kc) * 3 + f) * 1024;
        bf16x8 vh = *(const bf16x8*)(VW + vb + lane * 8);
        bf16x8 vl = *(const bf16x8*)(VW + vb + 512 + lane * 8);
        #pragma unroll
        for (int qs = 0; qs < 2; ++qs) {
          o[qs][f] = __builtin_amdgcn_mfma_f32_16x16x32_bf16(vh, pb[qs], o[qs][f], 0, 0, 0);
          o[qs][f] = __builtin_amdgcn_mfma_f32_16x16x32_bf16(vl, pb[qs], o[qs][f], 0, 0, 0);
        }
      }
    }
    __builtin_amdgcn_s_setprio(0);
  }

  // ---- tree-merge the 4 key-quarters (comb overlays plds) ----
  // slot(qt, qs, r): 14 floats per lane
  #define SLOT(qt_, qs_, r_) (comb + ((((qt_) * 2 + (qs_)) * 2 + (r_)) * 64 + lane) * 14)
  __syncthreads();
  if (kq & 1) {
    #pragma unroll
    for (int qs = 0; qs < 2; ++qs) {
      float* cb = SLOT(qt, qs, kq >> 1);
      #pragma unroll
      for (int f = 0; f < 3; ++f)
        #pragma unroll
        for (int r = 0; r < 4; ++r) cb[f * 4 + r] = o[qs][f][r];
      cb[12] = m[qs]; cb[13] = l[qs];
    }
  }
  __syncthreads();
  if (!(kq & 1)) {
    #pragma unroll
    for (int qs = 0; qs < 2; ++qs) {
      const float* cb = SLOT(qt, qs, kq >> 1);
      float m1 = cb[12], l1 = cb[13];
      float mn = fmaxf(m[qs], m1);
      float s0 = __builtin_amdgcn_exp2f(m[qs] - mn);
      float s1 = __builtin_amdgcn_exp2f(m1 - mn);
      l[qs] = l[qs] * s0 + l1 * s1;
      #pragma unroll
      for (int f = 0; f < 3; ++f)
        #pragma unroll
        for (int r = 0; r < 4; ++r)
          o[qs][f][r] = o[qs][f][r] * s0 + cb[f * 4 + r] * s1;
      m[qs] = mn;
    }
  }
  __syncthreads();
  if (kq == 2) {
    #pragma unroll
    for (int qs = 0; qs < 2; ++qs) {
      float* cb = SLOT(qt, qs, 1);
      #pragma unroll
      for (int f = 0; f < 3; ++f)
        #pragma unroll
        for (int r = 0; r < 4; ++r) cb[f * 4 + r] = o[qs][f][r];
      cb[12] = m[qs]; cb[13] = l[qs];
    }
  }
  __syncthreads();
  if (kq == 0) {
    const int h_ = hb >> 1, b_ = hb & 1;
    #pragma unroll
    for (int qs = 0; qs < 2; ++qs) {
      const float* cb = SLOT(qt, qs, 1);
      float m1 = cb[12], l1 = cb[13];
      float mn = fmaxf(m[qs], m1);
      float s0 = __builtin_amdgcn_exp2f(m[qs] - mn);
      float s1 = __builtin_amdgcn_exp2f(m1 - mn);
      float invl = 1.f / (l[qs] * s0 + l1 * s1);
      const int n = (tA + qs) * 16 + q;
      #pragma unroll
      for (int f = 0; f < 3; ++f) {
        float4 st4 = {(o[qs][f][0] * s0 + cb[f * 4 + 0] * s1) * invl,
                      (o[qs][f][1] * s0 + cb[f * 4 + 1] * s1) * invl,
                      (o[qs][f][2] * s0 + cb[f * 4 + 2] * s1) * invl,
                      (o[qs][f][3] * s0 + cb[f * 4 + 3] * s1) * invl};
        *(float4*)&Ob[(((size_t)(b_ * NN + n)) * 3 + f) * 128 + h_ * 16 + g * 4] = st4;
      }
    }
  }
  #undef SLOT
}

// ---------------------------------------------------------------------------
// out: out = ev_nonlin(resi @ w_out). 4 tokens / 128 threads.
// ---------------------------------------------------------------------------
__global__ __launch_bounds__(128) void out_kernel(
    const float* __restrict__ Ob, const float* __restrict__ w_out,
    const float* __restrict__ w1, const float* __restrict__ b1,
    const float* __restrict__ w2, const float* __restrict__ b2,
    float* __restrict__ out)
{
  const int t0 = blockIdx.x * TB;
  const int j = threadIdx.x;
  __shared__ float rs[TB][384];
  __shared__ float norm_s[TB][128];
  __shared__ float h_s[TB][64];

  {
    const float4* src = (const float4*)(Ob + (size_t)t0 * 384);
    float4* dst = (float4*)&rs[0][0];
    #pragma unroll
    for (int i = 0; i < 3; ++i) dst[j + i * 128] = src[j + i * 128];
  }
  __syncthreads();

  float p0[TB], p1[TB], p2[TB];
  #pragma unroll
  for (int t = 0; t < TB; ++t) { p0[t] = 0.f; p1[t] = 0.f; p2[t] = 0.f; }
  #pragma unroll 2
  for (int c = 0; c < 128; c += 4) {
    float w4[4];
    #pragma unroll
    for (int i = 0; i < 4; ++i) w4[i] = w_out[(c + i) * 128 + j];
    #pragma unroll
    for (int t = 0; t < TB; ++t) {
      float4 x0 = *(const float4*)&rs[t][c];
      float4 x1 = *(const float4*)&rs[t][128 + c];
      float4 x2 = *(const float4*)&rs[t][256 + c];
      p0[t] += x0.x * w4[0] + x0.y * w4[1] + x0.z * w4[2] + x0.w * w4[3];
      p1[t] += x1.x * w4[0] + x1.y * w4[1] + x1.z * w4[2] + x1.w * w4[3];
      p2[t] += x2.x * w4[0] + x2.y * w4[1] + x2.z * w4[2] + x2.w * w4[3];
    }
  }
  float np[TB]; int zmask = 0;
  #pragma unroll
  for (int t = 0; t < TB; ++t) {
    float nn = sqrtf(p0[t] * p0[t] + p1[t] * p1[t] + p2[t] * p2[t]);
    if (nn <= EPSV) zmask |= (1 << t);
    np[t] = nn + EPSV;
    norm_s[t][j] = np[t];
  }
  __syncthreads();

  {
    const int jc = j & 63;
    const int tb = (j >> 6) * 2;
    float a[2];
    float bb1 = b1[jc];
    #pragma unroll
    for (int u = 0; u < 2; ++u) a[u] = bb1;
    #pragma unroll 2
    for (int c = 0; c < 128; c += 4) {
      float w4[4];
      #pragma unroll
      for (int i = 0; i < 4; ++i) w4[i] = w1[(c + i) * 64 + jc];
      #pragma unroll
      for (int u = 0; u < 2; ++u) {
        float4 n4 = *(const float4*)&norm_s[tb + u][c];
        a[u] += n4.x * w4[0] + n4.y * w4[1] + n4.z * w4[2] + n4.w * w4[3];
      }
    }
    #pragma unroll
    for (int u = 0; u < 2; ++u)
      h_s[tb + u][jc] = a[u] > 0.f ? a[u] : NSL * a[u];
  }
  __syncthreads();

  float bn[TB];
  {
    float b2j = b2[j];
    #pragma unroll
    for (int t = 0; t < TB; ++t) bn[t] = b2j + np[t];
    #pragma unroll 2
    for (int i = 0; i < 64; i += 4) {
      float w4[4];
      #pragma unroll
      for (int ii = 0; ii < 4; ++ii) w4[ii] = w2[(i + ii) * 128 + j];
      #pragma unroll
      for (int t = 0; t < TB; ++t) {
        float4 h4 = *(const float4*)&h_s[t][i];
        bn[t] += h4.x * w4[0] + h4.y * w4[1] + h4.z * w4[2] + h4.w * w4[3];
      }
    }
  }
  #pragma unroll
  for (int t = 0; t < TB; ++t) {
    float ratio = (zmask >> t) & 1 ? 1.f : bn[t] / np[t];
    float* od = out + (size_t)(t0 + t) * 384;
    od[j] = p0[t] * ratio; od[128 + j] = p1[t] * ratio; od[256 + j] = p2[t] * ratio;
  }
}

// ---------------------------------------------------------------------------
extern "C" void kernel_launch(void* const* d_in, const int* in_sizes, int n_in,
                              void* d_out, int out_size, void* d_ws, size_t ws_size,
                              hipStream_t stream) {
  const float* qfts   = (const float*)d_in[0];
  const float* kvfts  = (const float*)d_in[1];
  const float* w_q_in = (const float*)d_in[2];
  const float* q_w1   = (const float*)d_in[3];
  const float* q_b1   = (const float*)d_in[4];
  const float* q_w2   = (const float*)d_in[5];
  const float* q_b2   = (const float*)d_in[6];
  const float* w_kv_in= (const float*)d_in[7];
  const float* kv_w1  = (const float*)d_in[8];
  const float* kv_b1  = (const float*)d_in[9];
  const float* kv_w2  = (const float*)d_in[10];
  const float* kv_b2  = (const float*)d_in[11];
  const float* w_q    = (const float*)d_in[12];
  const float* w_k    = (const float*)d_in[13];
  const float* w_v    = (const float*)d_in[14];
  const float* w_out  = (const float*)d_in[15];
  const float* o_w1   = (const float*)d_in[16];
  const float* o_b1   = (const float*)d_in[17];
  const float* o_w2   = (const float*)d_in[18];
  const float* o_b2   = (const float*)d_in[19];

  unsigned short* QW = (unsigned short*)d_ws;
  unsigned short* KW = QW + 3145728;
  unsigned short* VW = KW + 3145728;
  float* Obuf = (float*)(VW + 3145728);

  dim3 pg(BB * NN / TB, 2);
  pre_kernel<<<pg, 128, 0, stream>>>(qfts, kvfts,
                                     w_q_in, q_w1, q_b1, q_w2, q_b2,
                                     w_kv_in, kv_w1, kv_b1, kv_w2, kv_b2,
                                     w_q, w_k, w_v, QW, KW, VW);
  dim3 ag(32, 16);
  attn_kernel<<<ag, 512, 0, stream>>>(QW, KW, VW, Obuf);
  out_kernel<<<BB * NN / TB, 128, 0, stream>>>(Obuf, w_out, o_w1, o_b1, o_w2, o_b2, (float*)d_out);
}